// Round 1
// baseline (52491.272 us; speedup 1.0000x reference)
//
#include <hip/hip_runtime.h>
#include <hip/hip_bf16.h>
#include <math.h>
#include <limits.h>

#define N_PTSC 131072
#define GD 14
#define FEAT 128
#define HIDN 64
#define TBITS 19
#define TSIZE (1<<TBITS)
#define EMPTY_KEY (-1)
#define VOXEL 0.05f
#define EPSC 1e-5f
#define RED_BLOCKS 256
#define TV 48
#define NB_CONV ((N_PTSC + TV - 1)/TV)
#define PPB 32

// ---------------- workspace layout (bytes) ----------------
// hdr: hi[0..2]=vcmin, hi[3..5]=vcmax, hi[6..8]=mx, hi[9]=m12, hi[10]=nvox
//      hf[16..18]=mean ; doubles @+2048: bnsum[128], @+3072: bnsq[128]
//      floats @+4096: bnmean[128], @+4608: bnscale[128]
#define OFF_HDR   0
#define OFF_RED   8192
#define OFF_TKEY  16384
#define OFF_TSLOT (OFF_TKEY + (size_t)TSIZE*4)
#define OFF_TIDX  (OFF_TSLOT + (size_t)TSIZE*4)
#define OFF_INV   (OFF_TIDX + (size_t)N_PTSC*4)
#define OFF_VOXH  (OFF_INV + (size_t)N_PTSC*4)
#define OFF_CNT   (OFF_VOXH + (size_t)N_PTSC*4)
#define OFF_VC    (OFF_CNT + (size_t)N_PTSC*4)
#define OFF_NBR   (OFF_VC + (size_t)N_PTSC*12)
#define OFF_VF    (OFF_NBR + (size_t)N_PTSC*27*4)
#define OFF_B1    (OFF_VF + (size_t)N_PTSC*FEAT*4)
#define OFF_B2    (OFF_B1 + (size_t)N_PTSC*FEAT*4)
#define WS_NEED   (OFF_B2 + (size_t)N_PTSC*FEAT*4)

__device__ __forceinline__ float cleanf(float x){
  if(__builtin_isnan(x)) return 0.f;
  if(__builtin_isinf(x)) return x>0.f?1.f:-1.f;
  return x;
}
__device__ __forceinline__ float get_ps(const float* p){
  float v=p[0];
  return (__builtin_isfinite(v) && v!=0.f) ? v : 1.f;
}
__device__ __forceinline__ unsigned hashh(int h){
  return ((unsigned)h*2654435761u)>>(32-TBITS);
}

// ---------------- mean reduction (f64, deterministic tree) ----------------
__global__ __launch_bounds__(256) void k_red1(const float* __restrict__ gp, const float* __restrict__ psin,
                                              double* __restrict__ redp){
  float ps=get_ps(psin);
  int tid=threadIdx.x;
  double s0=0,s1=0,s2=0;
  for(int i=blockIdx.x*256+tid; i<N_PTSC; i+=RED_BLOCKS*256){
    const float* g=gp+(size_t)i*GD;
    s0+=(double)(cleanf(g[0])/ps);
    s1+=(double)(cleanf(g[1])/ps);
    s2+=(double)(cleanf(g[2])/ps);
  }
  __shared__ double sm[3][256];
  sm[0][tid]=s0; sm[1][tid]=s1; sm[2][tid]=s2;
  __syncthreads();
  for(int s=128;s>0;s>>=1){
    if(tid<s){ sm[0][tid]+=sm[0][tid+s]; sm[1][tid]+=sm[1][tid+s]; sm[2][tid]+=sm[2][tid+s]; }
    __syncthreads();
  }
  if(tid==0){ redp[blockIdx.x*3+0]=sm[0][0]; redp[blockIdx.x*3+1]=sm[1][0]; redp[blockIdx.x*3+2]=sm[2][0]; }
}

__global__ __launch_bounds__(256) void k_red2(const double* __restrict__ redp, int* __restrict__ hi, float* __restrict__ hf){
  int tid=threadIdx.x;
  __shared__ double sm[3][256];
  sm[0][tid]=redp[tid*3+0]; sm[1][tid]=redp[tid*3+1]; sm[2][tid]=redp[tid*3+2];
  __syncthreads();
  for(int s=128;s>0;s>>=1){
    if(tid<s){ sm[0][tid]+=sm[0][tid+s]; sm[1][tid]+=sm[1][tid+s]; sm[2][tid]+=sm[2][tid+s]; }
    __syncthreads();
  }
  if(tid==0){
    hf[16]=(float)(sm[0][0]/(double)N_PTSC);
    hf[17]=(float)(sm[1][0]/(double)N_PTSC);
    hf[18]=(float)(sm[2][0]/(double)N_PTSC);
    hi[0]=INT_MAX; hi[1]=INT_MAX; hi[2]=INT_MAX;
    hi[3]=INT_MIN; hi[4]=INT_MIN; hi[5]=INT_MIN;
    hi[10]=0;
  }
}

// ---------------- voxel coords + extents ----------------
__global__ __launch_bounds__(256) void k_vc(const float* __restrict__ gp, const float* __restrict__ psin,
                                            const float* __restrict__ hf, int* __restrict__ hi, int* __restrict__ vc){
  float ps=get_ps(psin);
  float m0=hf[16], m1=hf[17], m2=hf[18];
  int mn0=INT_MAX,mn1=INT_MAX,mn2=INT_MAX,mx0=INT_MIN,mx1=INT_MIN,mx2=INT_MIN;
  for(int i=blockIdx.x*blockDim.x+threadIdx.x; i<N_PTSC; i+=gridDim.x*blockDim.x){
    const float* g=gp+(size_t)i*GD;
    int v0=(int)floorf((cleanf(g[0])/ps - m0)/VOXEL);
    int v1=(int)floorf((cleanf(g[1])/ps - m1)/VOXEL);
    int v2=(int)floorf((cleanf(g[2])/ps - m2)/VOXEL);
    vc[i]=v0; vc[N_PTSC+i]=v1; vc[2*N_PTSC+i]=v2;
    mn0=min(mn0,v0); mn1=min(mn1,v1); mn2=min(mn2,v2);
    mx0=max(mx0,v0); mx1=max(mx1,v1); mx2=max(mx2,v2);
  }
  __shared__ int sb[6][256];
  int tid=threadIdx.x;
  sb[0][tid]=mn0; sb[1][tid]=mn1; sb[2][tid]=mn2;
  sb[3][tid]=mx0; sb[4][tid]=mx1; sb[5][tid]=mx2;
  __syncthreads();
  for(int s=128;s>0;s>>=1){
    if(tid<s){
      #pragma unroll
      for(int d=0;d<3;d++){
        sb[d][tid]=min(sb[d][tid],sb[d][tid+s]);
        sb[3+d][tid]=max(sb[3+d][tid],sb[3+d][tid+s]);
      }
    }
    __syncthreads();
  }
  if(tid==0){
    atomicMin(&hi[0],sb[0][0]); atomicMin(&hi[1],sb[1][0]); atomicMin(&hi[2],sb[2][0]);
    atomicMax(&hi[3],sb[3][0]); atomicMax(&hi[4],sb[4][0]); atomicMax(&hi[5],sb[5][0]);
  }
}

__global__ void k_grid(int* hi){
  if(threadIdx.x==0&&blockIdx.x==0){
    int mx0=hi[3]-hi[0]+1, mx1=hi[4]-hi[1]+1, mx2=hi[5]-hi[2]+1;
    hi[6]=mx0; hi[7]=mx1; hi[8]=mx2; hi[9]=mx1*mx2;
  }
}

// ---------------- hash insert + slot assignment ----------------
__global__ __launch_bounds__(256) void k_hash(const int* __restrict__ vc, const int* __restrict__ hi,
                                              int* __restrict__ tkeys, int* __restrict__ tidx){
  int i=blockIdx.x*256+threadIdx.x;
  if(i>=N_PTSC) return;
  int mn0=hi[0],mn1=hi[1],mn2=hi[2],mx2=hi[8],m12=hi[9];
  int h=(vc[i]-mn0)*m12 + (vc[N_PTSC+i]-mn1)*mx2 + (vc[2*N_PTSC+i]-mn2);
  unsigned idx=hashh(h);
  while(true){
    int k=atomicCAS(&tkeys[idx],EMPTY_KEY,h);
    if(k==EMPTY_KEY||k==h) break;
    idx=(idx+1)&(TSIZE-1);
  }
  tidx[i]=(int)idx;
}

__global__ __launch_bounds__(256) void k_slot(const int* __restrict__ tkeys, int* __restrict__ tslot,
                                              int* __restrict__ voxh, int* __restrict__ hi){
  int t=blockIdx.x*256+threadIdx.x;
  if(t>=TSIZE) return;
  int k=tkeys[t];
  if(k!=EMPTY_KEY){
    int s=atomicAdd(&hi[10],1);
    tslot[t]=s;
    voxh[s]=k;
  }
}

// ---------------- input encoder + LN + ReLU + mean-pool ----------------
__global__ __launch_bounds__(128) void k_pool(const float* __restrict__ gp,
    const float* __restrict__ w_in, const float* __restrict__ b_in,
    const float* __restrict__ ln_g, const float* __restrict__ ln_b,
    const int* __restrict__ tidx, const int* __restrict__ tslot,
    int* __restrict__ inv, int* __restrict__ cnt, float* __restrict__ vf){
  int p=blockIdx.x, c=threadIdx.x;
  __shared__ float grow[GD];
  __shared__ float red[FEAT];
  if(c<GD) grow[c]=cleanf(gp[(size_t)p*GD+c]);
  __syncthreads();
  float acc=b_in[c];
  #pragma unroll
  for(int k=0;k<GD;k++) acc=fmaf(grow[k], w_in[k*FEAT+c], acc);
  red[c]=acc; __syncthreads();
  #pragma unroll
  for(int s=64;s>0;s>>=1){ if(c<s) red[c]+=red[c+s]; __syncthreads(); }
  float mu=red[0]*(1.f/FEAT);
  __syncthreads();
  float d=acc-mu;
  red[c]=d*d; __syncthreads();
  #pragma unroll
  for(int s=64;s>0;s>>=1){ if(c<s) red[c]+=red[c+s]; __syncthreads(); }
  float var=red[0]*(1.f/FEAT);
  float y=fmaxf(d*rsqrtf(var+EPSC)*ln_g[c]+ln_b[c], 0.f);
  int slot=tslot[tidx[p]];
  if(c==0){ inv[p]=slot; atomicAdd(&cnt[slot],1); }
  atomicAdd(&vf[(size_t)slot*FEAT+c], y);
}

__global__ __launch_bounds__(256) void k_div(float* __restrict__ vf, const int* __restrict__ cnt,
                                             const int* __restrict__ hi){
  int M=hi[10];
  int total=M*FEAT;
  for(int i=blockIdx.x*blockDim.x+threadIdx.x; i<total; i+=gridDim.x*blockDim.x){
    int slot=i>>7;
    vf[i]=vf[i]/(float)max(cnt[slot],1);
  }
}

// ---------------- neighbor table (27 taps per active voxel) ----------------
__global__ __launch_bounds__(256) void k_nbr(const int* __restrict__ voxh, const int* __restrict__ tkeys,
                                             const int* __restrict__ tslot, const int* __restrict__ hi,
                                             int* __restrict__ nbr){
  int M=hi[10];
  int mx0=hi[6],mx1=hi[7],mx2=hi[8],m12=hi[9];
  int total=M*27;
  for(int i=blockIdx.x*blockDim.x+threadIdx.x; i<total; i+=gridDim.x*blockDim.x){
    int s=i/27, k=i-s*27;
    int h=voxh[s];
    int c0=h/m12; int r=h-c0*m12; int c1=r/mx2; int c2=r-c1*mx2;
    int n0=c0+k/9-1, n1=c1+(k/3)%3-1, n2=c2+k%3-1;
    int res=-1;
    if(n0>=0&&n0<mx0&&n1>=0&&n1<mx1&&n2>=0&&n2<mx2){
      int nh=n0*m12+n1*mx2+n2;
      unsigned idx=hashh(nh);
      while(true){
        int kk=tkeys[idx];
        if(kk==nh){ res=tslot[idx]; break; }
        if(kk==EMPTY_KEY) break;
        idx=(idx+1)&(TSIZE-1);
      }
    }
    nbr[i]=res;
  }
}

// ---------------- submanifold conv: Y[v] = sum_k X[nbr(v,k)] @ W[k] ----------------
// block=256 (4 waves), TV=48 voxels/block; wave w owns voxels w+4*vi (vi<12);
// lane owns out-channels {lane, lane+64}. W[k] in LDS with 16B-granule XOR swizzle
// (conflict-free b128 reads). Per-voxel found-skip is wave-uniform.
__global__ __launch_bounds__(256) void k_conv(const float* __restrict__ X, float* __restrict__ Y,
      const float* __restrict__ Wg, const int* __restrict__ nbr, const int* __restrict__ hi){
  int M=hi[10];
  int v0=blockIdx.x*TV;
  if(v0>=M) return;
  __shared__ float Ws[FEAT*FEAT];   // 64 KB, swizzled [ch][c]
  __shared__ float Xs[TV*FEAT];     // 24 KB
  __shared__ int nbs[TV];
  int tid=threadIdx.x;
  int wave=tid>>6, lane=tid&63;
  float acc[12][2];
  #pragma unroll
  for(int i=0;i<12;i++){ acc[i][0]=0.f; acc[i][1]=0.f; }
  for(int k=0;k<27;k++){
    __syncthreads();  // previous compute done
    if(tid<TV){ int v=v0+tid; nbs[tid]=(v<M)?nbr[(size_t)v*27+k]:-1; }
    __syncthreads();  // nbs visible
    const float4* wk=(const float4*)(Wg+(size_t)k*FEAT*FEAT);
    #pragma unroll
    for(int j=0;j<16;j++){
      int f=j*256+tid;
      float4 w=wk[f];
      int c=f>>5;
      int c4=c>>2, cl=c&3;
      int ch0=(f&31)*4;
      Ws[(ch0  )*128 + ((c4^((ch0  )&31))<<2) + cl]=w.x;
      Ws[(ch0+1)*128 + ((c4^((ch0+1)&31))<<2) + cl]=w.y;
      Ws[(ch0+2)*128 + ((c4^((ch0+2)&31))<<2) + cl]=w.z;
      Ws[(ch0+3)*128 + ((c4^((ch0+3)&31))<<2) + cl]=w.w;
    }
    #pragma unroll
    for(int j=0;j<6;j++){
      int f=j*256+tid;
      int v=f>>5, c4=f&31;
      int nb=nbs[v];
      float4 x=(nb>=0)?((const float4*)(X+(size_t)nb*FEAT))[c4]:make_float4(0.f,0.f,0.f,0.f);
      ((float4*)Xs)[f]=x;
    }
    __syncthreads();  // stages visible
    unsigned fmask=0;
    #pragma unroll
    for(int vi=0;vi<12;vi++) if(nbs[wave+4*vi]>=0) fmask|=(1u<<vi);
    if(fmask==0) continue;
    #pragma unroll 4
    for(int c=0;c<FEAT;c+=4){
      int swz=((c>>2)^(lane&31))<<2;
      float4 w0=*(const float4*)&Ws[lane*128+swz];
      float4 w1=*(const float4*)&Ws[(lane+64)*128+swz];
      #pragma unroll
      for(int vi=0;vi<12;vi++){
        if(!((fmask>>vi)&1u)) continue;
        float4 xb=*(const float4*)&Xs[(wave+4*vi)*128+c];
        acc[vi][0]=fmaf(xb.w,w0.w,fmaf(xb.z,w0.z,fmaf(xb.y,w0.y,fmaf(xb.x,w0.x,acc[vi][0]))));
        acc[vi][1]=fmaf(xb.w,w1.w,fmaf(xb.z,w1.z,fmaf(xb.y,w1.y,fmaf(xb.x,w1.x,acc[vi][1]))));
      }
    }
  }
  #pragma unroll
  for(int vi=0;vi<12;vi++){
    int v=v0+wave+4*vi;
    if(v<M){
      Y[(size_t)v*FEAT+lane]=acc[vi][0];
      Y[(size_t)v*FEAT+64+lane]=acc[vi][1];
    }
  }
}

// ---------------- batch norm ----------------
__global__ __launch_bounds__(128) void k_bnstat(const float* __restrict__ buf, const int* __restrict__ hi,
                                                double* __restrict__ bnsum, double* __restrict__ bnsq){
  int M=hi[10]; int c=threadIdx.x;
  float s=0.f,s2=0.f;
  for(int r=blockIdx.x; r<M; r+=gridDim.x){
    float v=buf[(size_t)r*FEAT+c];
    s+=v; s2+=v*v;
  }
  atomicAdd(&bnsum[c],(double)s);
  atomicAdd(&bnsq[c],(double)s2);
}

__global__ void k_bnfinish(const double* __restrict__ bnsum, const double* __restrict__ bnsq,
                           const int* __restrict__ hi, const float* __restrict__ g,
                           float* __restrict__ bnmean, float* __restrict__ bnscale){
  int c=threadIdx.x;
  double M=(double)(hi[10]>0?hi[10]:1);
  double mu=bnsum[c]/M;
  double var=bnsq[c]/M-mu*mu;
  if(var<0.0) var=0.0;
  bnmean[c]=(float)mu;
  bnscale[c]=(float)(1.0/sqrt(var+(double)EPSC))*g[c];
}

__global__ __launch_bounds__(256) void k_bnapply_relu(float* __restrict__ buf,
      const float* __restrict__ bnmean, const float* __restrict__ bnscale,
      const float* __restrict__ bnb, const int* __restrict__ hi){
  int M=hi[10]; int total=M*FEAT;
  for(int i=blockIdx.x*blockDim.x+threadIdx.x; i<total; i+=gridDim.x*blockDim.x){
    int c=i&127;
    buf[i]=fmaxf((buf[i]-bnmean[c])*bnscale[c]+bnb[c], 0.f);
  }
}

__global__ __launch_bounds__(256) void k_bnapply_res(const float* __restrict__ buf, float* __restrict__ vf,
      const float* __restrict__ bnmean, const float* __restrict__ bnscale,
      const float* __restrict__ bnb, const int* __restrict__ hi){
  int M=hi[10]; int total=M*FEAT;
  for(int i=blockIdx.x*blockDim.x+threadIdx.x; i<total; i+=gridDim.x*blockDim.x){
    int c=i&127;
    vf[i]=fmaxf((buf[i]-bnmean[c])*bnscale[c]+bnb[c]+vf[i], 0.f);
  }
}

// ---------------- output head: relu(pf@W1+b1)@W2+b2 ----------------
__global__ __launch_bounds__(256) void k_head(const float* __restrict__ vf, const int* __restrict__ inv,
    const float* __restrict__ w1, const float* __restrict__ b1,
    const float* __restrict__ w2, const float* __restrict__ b2, float* __restrict__ out){
  __shared__ float w1s[FEAT*HIDN];
  __shared__ float w2s[HIDN*GD];
  __shared__ float hs[PPB*HIDN];
  int tid=threadIdx.x;
  for(int i=tid;i<FEAT*HIDN;i+=256) w1s[i]=w1[i];
  for(int i=tid;i<HIDN*GD;i+=256) w2s[i]=w2[i];
  __syncthreads();
  int p0=blockIdx.x*PPB;
  int hid=tid&63, pl=tid>>6;
  float bb=b1[hid];
  for(int pp=pl; pp<PPB; pp+=4){
    const float* pf=vf+(size_t)inv[p0+pp]*FEAT;
    float a=bb;
    #pragma unroll 4
    for(int c=0;c<FEAT;c++) a=fmaf(pf[c], w1s[c*HIDN+hid], a);
    hs[pp*HIDN+hid]=fmaxf(a,0.f);
  }
  __syncthreads();
  for(int i=tid;i<PPB*GD;i+=256){
    int pp=i/GD, o=i-pp*GD;
    const float* h=&hs[pp*HIDN];
    float a=b2[o];
    #pragma unroll
    for(int j=0;j<HIDN;j++) a=fmaf(h[j], w2s[j*GD+o], a);
    out[(size_t)(p0+pp)*GD+o]=a;
  }
}

extern "C" void kernel_launch(void* const* d_in, const int* in_sizes, int n_in,
                              void* d_out, int out_size, void* d_ws, size_t ws_size,
                              hipStream_t stream) {
  if(ws_size < WS_NEED) return;  // ~212 MiB required
  const float* gp  =(const float*)d_in[0];
  const float* psin=(const float*)d_in[1];
  const float* w_in=(const float*)d_in[2];
  const float* b_in=(const float*)d_in[3];
  const float* ln_g=(const float*)d_in[4];
  const float* ln_b=(const float*)d_in[5];
  const float* cw1 =(const float*)d_in[6];
  const float* bn1g=(const float*)d_in[7];
  const float* bn1b=(const float*)d_in[8];
  const float* cw2 =(const float*)d_in[9];
  const float* bn2g=(const float*)d_in[10];
  const float* bn2b=(const float*)d_in[11];
  const float* wh1 =(const float*)d_in[12];
  const float* bh1 =(const float*)d_in[13];
  const float* wh2 =(const float*)d_in[14];
  const float* bh2 =(const float*)d_in[15];
  float* out=(float*)d_out;

  char* ws=(char*)d_ws;
  int*    hi    =(int*)(ws+OFF_HDR);
  float*  hf    =(float*)(ws+OFF_HDR);
  double* bnsum =(double*)(ws+OFF_HDR+2048);
  double* bnsq  =(double*)(ws+OFF_HDR+3072);
  float*  bnmean=(float*)(ws+OFF_HDR+4096);
  float*  bnscal=(float*)(ws+OFF_HDR+4608);
  double* redp  =(double*)(ws+OFF_RED);
  int*    tkeys =(int*)(ws+OFF_TKEY);
  int*    tslot =(int*)(ws+OFF_TSLOT);
  int*    tidx  =(int*)(ws+OFF_TIDX);
  int*    inv   =(int*)(ws+OFF_INV);
  int*    voxh  =(int*)(ws+OFF_VOXH);
  int*    cnt   =(int*)(ws+OFF_CNT);
  int*    vc    =(int*)(ws+OFF_VC);
  int*    nbr   =(int*)(ws+OFF_NBR);
  float*  vf    =(float*)(ws+OFF_VF);
  float*  b1buf =(float*)(ws+OFF_B1);
  float*  b2buf =(float*)(ws+OFF_B2);

  hipMemsetAsync(tkeys,0xFF,(size_t)TSIZE*4,stream);
  hipMemsetAsync(vf,0,(size_t)N_PTSC*FEAT*4,stream);
  hipMemsetAsync(cnt,0,(size_t)N_PTSC*4,stream);

  k_red1<<<RED_BLOCKS,256,0,stream>>>(gp,psin,redp);
  k_red2<<<1,256,0,stream>>>(redp,hi,hf);
  k_vc<<<256,256,0,stream>>>(gp,psin,hf,hi,vc);
  k_grid<<<1,64,0,stream>>>(hi);
  k_hash<<<N_PTSC/256,256,0,stream>>>(vc,hi,tkeys,tidx);
  k_slot<<<TSIZE/256,256,0,stream>>>(tkeys,tslot,voxh,hi);
  k_pool<<<N_PTSC,128,0,stream>>>(gp,w_in,b_in,ln_g,ln_b,tidx,tslot,inv,cnt,vf);
  k_div<<<2048,256,0,stream>>>(vf,cnt,hi);
  k_nbr<<<2048,256,0,stream>>>(voxh,tkeys,tslot,hi,nbr);

  for(int l=0;l<2;l++){
    k_conv<<<NB_CONV,256,0,stream>>>(vf,b1buf,cw1+(size_t)l*27*FEAT*FEAT,nbr,hi);
    hipMemsetAsync(bnsum,0,2048,stream);
    k_bnstat<<<512,128,0,stream>>>(b1buf,hi,bnsum,bnsq);
    k_bnfinish<<<1,128,0,stream>>>(bnsum,bnsq,hi,bn1g+(size_t)l*FEAT,bnmean,bnscal);
    k_bnapply_relu<<<2048,256,0,stream>>>(b1buf,bnmean,bnscal,bn1b+(size_t)l*FEAT,hi);

    k_conv<<<NB_CONV,256,0,stream>>>(b1buf,b2buf,cw2+(size_t)l*27*FEAT*FEAT,nbr,hi);
    hipMemsetAsync(bnsum,0,2048,stream);
    k_bnstat<<<512,128,0,stream>>>(b2buf,hi,bnsum,bnsq);
    k_bnfinish<<<1,128,0,stream>>>(bnsum,bnsq,hi,bn2g+(size_t)l*FEAT,bnmean,bnscal);
    k_bnapply_res<<<2048,256,0,stream>>>(b2buf,vf,bnmean,bnscal,bn2b+(size_t)l*FEAT,hi);
  }

  k_head<<<N_PTSC/PPB,256,0,stream>>>(vf,inv,wh1,bh1,wh2,bh2,out);
}

// Round 2
// 2829.800 us; speedup vs baseline: 18.5495x; 18.5495x over previous
//
#include <hip/hip_runtime.h>
#include <hip/hip_bf16.h>
#include <math.h>
#include <limits.h>

#define N_PTSC 131072
#define GD 14
#define FEAT 128
#define HIDN 64
#define TBITS 19
#define TSIZE (1<<TBITS)
#define EMPTY_KEY (-1)
#define VOXEL 0.05f
#define EPSC 1e-5f
#define RED_BLOCKS 256
#define PPB 32

typedef __attribute__((ext_vector_type(8))) short short8;
typedef __attribute__((ext_vector_type(4))) float f32x4;

// ---------------- workspace layout (bytes) ----------------
#define OFF_HDR   0
#define OFF_RED   8192
#define OFF_TKEY  16384
#define OFF_TSLOT (OFF_TKEY + (size_t)TSIZE*4)
#define OFF_TIDX  (OFF_TSLOT + (size_t)TSIZE*4)
#define OFF_INV   (OFF_TIDX + (size_t)N_PTSC*4)
#define OFF_VOXH  (OFF_INV + (size_t)N_PTSC*4)
#define OFF_CNT   (OFF_VOXH + (size_t)N_PTSC*4)
#define OFF_VC    (OFF_CNT + (size_t)N_PTSC*4)
#define OFF_NBR   (OFF_VC + (size_t)N_PTSC*12)
#define OFF_WT    (OFF_NBR + (size_t)N_PTSC*27*4)
#define OFF_XBF   (OFF_WT + (size_t)4*27*FEAT*FEAT*2)
#define OFF_VF    (OFF_XBF + (size_t)N_PTSC*FEAT*2)
#define OFF_YB    (OFF_VF + (size_t)N_PTSC*FEAT*4)
#define WS_NEED   (OFF_YB + (size_t)N_PTSC*FEAT*4)

__device__ __forceinline__ float cleanf(float x){
  if(__builtin_isnan(x)) return 0.f;
  if(__builtin_isinf(x)) return x>0.f?1.f:-1.f;
  return x;
}
__device__ __forceinline__ float get_ps(const float* p){
  float v=p[0];
  return (__builtin_isfinite(v) && v!=0.f) ? v : 1.f;
}
__device__ __forceinline__ unsigned hashh(int h){
  return ((unsigned)h*2654435761u)>>(32-TBITS);
}
__device__ __forceinline__ unsigned short f2bf(float x){
  __hip_bfloat16 h=__float2bfloat16(x);
  return *reinterpret_cast<unsigned short*>(&h);
}

// ---------------- mean reduction ----------------
__global__ __launch_bounds__(256) void k_red1(const float* __restrict__ gp, const float* __restrict__ psin,
                                              double* __restrict__ redp){
  float ps=get_ps(psin);
  int tid=threadIdx.x;
  double s0=0,s1=0,s2=0;
  for(int i=blockIdx.x*256+tid; i<N_PTSC; i+=RED_BLOCKS*256){
    const float* g=gp+(size_t)i*GD;
    s0+=(double)(cleanf(g[0])/ps);
    s1+=(double)(cleanf(g[1])/ps);
    s2+=(double)(cleanf(g[2])/ps);
  }
  __shared__ double sm[3][256];
  sm[0][tid]=s0; sm[1][tid]=s1; sm[2][tid]=s2;
  __syncthreads();
  for(int s=128;s>0;s>>=1){
    if(tid<s){ sm[0][tid]+=sm[0][tid+s]; sm[1][tid]+=sm[1][tid+s]; sm[2][tid]+=sm[2][tid+s]; }
    __syncthreads();
  }
  if(tid==0){ redp[blockIdx.x*3+0]=sm[0][0]; redp[blockIdx.x*3+1]=sm[1][0]; redp[blockIdx.x*3+2]=sm[2][0]; }
}

__global__ __launch_bounds__(256) void k_red2(const double* __restrict__ redp, int* __restrict__ hi, float* __restrict__ hf){
  int tid=threadIdx.x;
  __shared__ double sm[3][256];
  sm[0][tid]=redp[tid*3+0]; sm[1][tid]=redp[tid*3+1]; sm[2][tid]=redp[tid*3+2];
  __syncthreads();
  for(int s=128;s>0;s>>=1){
    if(tid<s){ sm[0][tid]+=sm[0][tid+s]; sm[1][tid]+=sm[1][tid+s]; sm[2][tid]+=sm[2][tid+s]; }
    __syncthreads();
  }
  if(tid==0){
    hf[16]=(float)(sm[0][0]/(double)N_PTSC);
    hf[17]=(float)(sm[1][0]/(double)N_PTSC);
    hf[18]=(float)(sm[2][0]/(double)N_PTSC);
    hi[0]=INT_MAX; hi[1]=INT_MAX; hi[2]=INT_MAX;
    hi[3]=INT_MIN; hi[4]=INT_MIN; hi[5]=INT_MIN;
    hi[10]=0;
  }
}

// ---------------- voxel coords + extents ----------------
__global__ __launch_bounds__(256) void k_vc(const float* __restrict__ gp, const float* __restrict__ psin,
                                            const float* __restrict__ hf, int* __restrict__ hi, int* __restrict__ vc){
  float ps=get_ps(psin);
  float m0=hf[16], m1=hf[17], m2=hf[18];
  int mn0=INT_MAX,mn1=INT_MAX,mn2=INT_MAX,mx0=INT_MIN,mx1=INT_MIN,mx2=INT_MIN;
  for(int i=blockIdx.x*blockDim.x+threadIdx.x; i<N_PTSC; i+=gridDim.x*blockDim.x){
    const float* g=gp+(size_t)i*GD;
    int v0=(int)floorf((cleanf(g[0])/ps - m0)/VOXEL);
    int v1=(int)floorf((cleanf(g[1])/ps - m1)/VOXEL);
    int v2=(int)floorf((cleanf(g[2])/ps - m2)/VOXEL);
    vc[i]=v0; vc[N_PTSC+i]=v1; vc[2*N_PTSC+i]=v2;
    mn0=min(mn0,v0); mn1=min(mn1,v1); mn2=min(mn2,v2);
    mx0=max(mx0,v0); mx1=max(mx1,v1); mx2=max(mx2,v2);
  }
  __shared__ int sb[6][256];
  int tid=threadIdx.x;
  sb[0][tid]=mn0; sb[1][tid]=mn1; sb[2][tid]=mn2;
  sb[3][tid]=mx0; sb[4][tid]=mx1; sb[5][tid]=mx2;
  __syncthreads();
  for(int s=128;s>0;s>>=1){
    if(tid<s){
      #pragma unroll
      for(int d=0;d<3;d++){
        sb[d][tid]=min(sb[d][tid],sb[d][tid+s]);
        sb[3+d][tid]=max(sb[3+d][tid],sb[3+d][tid+s]);
      }
    }
    __syncthreads();
  }
  if(tid==0){
    atomicMin(&hi[0],sb[0][0]); atomicMin(&hi[1],sb[1][0]); atomicMin(&hi[2],sb[2][0]);
    atomicMax(&hi[3],sb[3][0]); atomicMax(&hi[4],sb[4][0]); atomicMax(&hi[5],sb[5][0]);
  }
}

__global__ void k_grid(int* hi){
  if(threadIdx.x==0&&blockIdx.x==0){
    int mx0=hi[3]-hi[0]+1, mx1=hi[4]-hi[1]+1, mx2=hi[5]-hi[2]+1;
    hi[6]=mx0; hi[7]=mx1; hi[8]=mx2; hi[9]=mx1*mx2;
  }
}

// ---------------- hash insert + slot assignment ----------------
__global__ __launch_bounds__(256) void k_hash(const int* __restrict__ vc, const int* __restrict__ hi,
                                              int* __restrict__ tkeys, int* __restrict__ tidx){
  int i=blockIdx.x*256+threadIdx.x;
  if(i>=N_PTSC) return;
  int mn0=hi[0],mn1=hi[1],mn2=hi[2],mx2=hi[8],m12=hi[9];
  int h=(vc[i]-mn0)*m12 + (vc[N_PTSC+i]-mn1)*mx2 + (vc[2*N_PTSC+i]-mn2);
  unsigned idx=hashh(h);
  while(true){
    int k=atomicCAS(&tkeys[idx],EMPTY_KEY,h);
    if(k==EMPTY_KEY||k==h) break;
    idx=(idx+1)&(TSIZE-1);
  }
  tidx[i]=(int)idx;
}

__global__ __launch_bounds__(256) void k_slot(const int* __restrict__ tkeys, int* __restrict__ tslot,
                                              int* __restrict__ voxh, int* __restrict__ hi){
  int t=blockIdx.x*256+threadIdx.x;
  if(t>=TSIZE) return;
  int k=tkeys[t];
  if(k!=EMPTY_KEY){
    int s=atomicAdd(&hi[10],1);
    tslot[t]=s;
    voxh[s]=k;
  }
}

// ---------------- weight prep: transpose + bf16 ----------------
// wt[(lc*27+k)*16384 + o*128 + i] = W[l][k][i][o], lc = l*2+c
__global__ __launch_bounds__(256) void k_wprep(const float* __restrict__ w1, const float* __restrict__ w2,
                                               unsigned short* __restrict__ wt){
  int t=blockIdx.x*256+threadIdx.x;
  int i=t&127, o=(t>>7)&127, r=t>>14;
  int k=r%27, lc=r/27;
  int l=lc>>1, c=lc&1;
  const float* src=(c==0)?w1:w2;
  wt[t]=f2bf(src[(((size_t)l*27+k)*128+i)*128+o]);
}

// ---------------- input encoder + LN + ReLU + mean-pool (wave per point) ----------------
__global__ __launch_bounds__(256) void k_pool(const float* __restrict__ gp,
    const float* __restrict__ w_in, const float* __restrict__ b_in,
    const float* __restrict__ ln_g, const float* __restrict__ ln_b,
    const int* __restrict__ tidx, const int* __restrict__ tslot,
    int* __restrict__ inv, int* __restrict__ cnt, float* __restrict__ vf){
  int p=blockIdx.x*4+(threadIdx.x>>6);
  int l=threadIdx.x&63;
  float x[GD];
  #pragma unroll
  for(int j=0;j<GD;j++) x[j]=cleanf(gp[(size_t)p*GD+j]);
  float a0=b_in[l], a1=b_in[l+64];
  #pragma unroll
  for(int j=0;j<GD;j++){
    a0=fmaf(x[j], w_in[j*FEAT+l], a0);
    a1=fmaf(x[j], w_in[j*FEAT+64+l], a1);
  }
  float s=a0+a1;
  #pragma unroll
  for(int off=32;off>0;off>>=1) s+=__shfl_xor(s,off);
  float mu=s*(1.f/FEAT);
  float d0=a0-mu, d1=a1-mu;
  float q=d0*d0+d1*d1;
  #pragma unroll
  for(int off=32;off>0;off>>=1) q+=__shfl_xor(q,off);
  float rs=rsqrtf(q*(1.f/FEAT)+EPSC);
  float y0=fmaxf(d0*rs*ln_g[l]+ln_b[l],0.f);
  float y1=fmaxf(d1*rs*ln_g[64+l]+ln_b[64+l],0.f);
  int slot=tslot[tidx[p]];
  if(l==0){ inv[p]=slot; atomicAdd(&cnt[slot],1); }
  atomicAdd(&vf[(size_t)slot*FEAT+l], y0);
  atomicAdd(&vf[(size_t)slot*FEAT+64+l], y1);
}

__global__ __launch_bounds__(256) void k_div(float* __restrict__ vf, unsigned short* __restrict__ xbf,
                                             const int* __restrict__ cnt, const int* __restrict__ hi){
  int M=hi[10];
  int total=M*FEAT;
  for(int i=blockIdx.x*blockDim.x+threadIdx.x; i<total; i+=gridDim.x*blockDim.x){
    int slot=i>>7;
    float v=vf[i]/(float)max(cnt[slot],1);
    vf[i]=v;
    xbf[i]=f2bf(v);
  }
}

// ---------------- neighbor table ----------------
__global__ __launch_bounds__(256) void k_nbr(const int* __restrict__ voxh, const int* __restrict__ tkeys,
                                             const int* __restrict__ tslot, const int* __restrict__ hi,
                                             int* __restrict__ nbr){
  int M=hi[10];
  int mx0=hi[6],mx1=hi[7],mx2=hi[8],m12=hi[9];
  int total=M*27;
  for(int i=blockIdx.x*blockDim.x+threadIdx.x; i<total; i+=gridDim.x*blockDim.x){
    int s=i/27, k=i-s*27;
    int h=voxh[s];
    int c0=h/m12; int r=h-c0*m12; int c1=r/mx2; int c2=r-c1*mx2;
    int n0=c0+k/9-1, n1=c1+(k/3)%3-1, n2=c2+k%3-1;
    int res=-1;
    if(n0>=0&&n0<mx0&&n1>=0&&n1<mx1&&n2>=0&&n2<mx2){
      int nh=n0*m12+n1*mx2+n2;
      unsigned idx=hashh(nh);
      while(true){
        int kk=tkeys[idx];
        if(kk==nh){ res=tslot[idx]; break; }
        if(kk==EMPTY_KEY) break;
        idx=(idx+1)&(TSIZE-1);
      }
    }
    nbr[i]=res;
  }
}

// ---------------- submanifold conv via MFMA bf16, no LDS ----------------
// Block: 256 thr = 4 waves, 128 voxels. Wave w owns voxels [v0+32w, v0+32w+32)
// = 2 row-tiles of 16, all 128 out-channels (8 col-tiles of 16).
// Per tap k: A = gathered X rows (bf16), B = wt[k] (out-major, in contiguous).
// A and B fragments use the same (group,j)->k bijection (contiguous 8), so the
// MFMA dot product is correct independent of the HW's internal k ordering.
// C/D layout: col=lane&15, row=4*(lane>>4)+reg (HW-verified).
__global__ __launch_bounds__(256) void k_conv(const unsigned short* __restrict__ X,
      float* __restrict__ Y, const unsigned short* __restrict__ Wt,
      const int* __restrict__ nbr, const int* __restrict__ hi){
  int M=hi[10];
  int v0=blockIdx.x*128;
  if(v0>=M) return;
  int tid=threadIdx.x;
  int w=tid>>6, l=tid&63;
  int g=l>>4, ln=l&15;
  int r0=v0+w*32+ln;          // rt=0 row for this lane
  f32x4 acc[2][8];
  #pragma unroll
  for(int rt=0;rt<2;rt++)
    #pragma unroll
    for(int nt=0;nt<8;nt++)
      acc[rt][nt]=(f32x4){0.f,0.f,0.f,0.f};
  short8 zfrag={0,0,0,0,0,0,0,0};
  for(int k=0;k<27;k++){
    int nb0=(r0<M)?nbr[(size_t)r0*27+k]:-1;
    int nb1=(r0+16<M)?nbr[(size_t)(r0+16)*27+k]:-1;
    if(__ballot(nb0>=0||nb1>=0)==0ull) continue;
    short8 a0[4], a1[4];
    #pragma unroll
    for(int ks=0;ks<4;ks++){
      a0[ks]=zfrag; a1[ks]=zfrag;
      if(nb0>=0) a0[ks]=*(const short8*)(X+(size_t)nb0*FEAT+ks*32+g*8);
      if(nb1>=0) a1[ks]=*(const short8*)(X+(size_t)nb1*FEAT+ks*32+g*8);
    }
    const unsigned short* wk=Wt+(size_t)k*FEAT*FEAT;
    #pragma unroll
    for(int nt=0;nt<8;nt++){
      const unsigned short* wb=wk+(size_t)(nt*16+ln)*FEAT+g*8;
      #pragma unroll
      for(int ks=0;ks<4;ks++){
        short8 b=*(const short8*)(wb+ks*32);
        acc[0][nt]=__builtin_amdgcn_mfma_f32_16x16x32_bf16(a0[ks],b,acc[0][nt],0,0,0);
        acc[1][nt]=__builtin_amdgcn_mfma_f32_16x16x32_bf16(a1[ks],b,acc[1][nt],0,0,0);
      }
    }
  }
  #pragma unroll
  for(int rt=0;rt<2;rt++){
    int vbase=v0+w*32+rt*16+g*4;
    #pragma unroll
    for(int r=0;r<4;r++){
      int v=vbase+r;
      if(v<M){
        #pragma unroll
        for(int nt=0;nt<8;nt++)
          Y[(size_t)v*FEAT+nt*16+ln]=acc[rt][nt][r];
      }
    }
  }
}

// ---------------- batch norm ----------------
__global__ __launch_bounds__(128) void k_bnstat(const float* __restrict__ buf, const int* __restrict__ hi,
                                                double* __restrict__ bnsum, double* __restrict__ bnsq){
  int M=hi[10]; int c=threadIdx.x;
  float s=0.f,s2=0.f;
  for(int r=blockIdx.x; r<M; r+=gridDim.x){
    float v=buf[(size_t)r*FEAT+c];
    s+=v; s2+=v*v;
  }
  atomicAdd(&bnsum[c],(double)s);
  atomicAdd(&bnsq[c],(double)s2);
}

__global__ void k_bnfinish(const double* __restrict__ bnsum, const double* __restrict__ bnsq,
                           const int* __restrict__ hi, const float* __restrict__ g,
                           float* __restrict__ bnmean, float* __restrict__ bnscale){
  int c=threadIdx.x;
  double M=(double)(hi[10]>0?hi[10]:1);
  double mu=bnsum[c]/M;
  double var=bnsq[c]/M-mu*mu;
  if(var<0.0) var=0.0;
  bnmean[c]=(float)mu;
  bnscale[c]=(float)(1.0/sqrt(var+(double)EPSC))*g[c];
}

__global__ __launch_bounds__(256) void k_bnapply_relu(const float* __restrict__ buf, unsigned short* __restrict__ xbf,
      const float* __restrict__ bnmean, const float* __restrict__ bnscale,
      const float* __restrict__ bnb, const int* __restrict__ hi){
  int M=hi[10]; int total=M*FEAT;
  for(int i=blockIdx.x*blockDim.x+threadIdx.x; i<total; i+=gridDim.x*blockDim.x){
    int c=i&127;
    xbf[i]=f2bf(fmaxf((buf[i]-bnmean[c])*bnscale[c]+bnb[c], 0.f));
  }
}

__global__ __launch_bounds__(256) void k_bnapply_res(const float* __restrict__ buf, float* __restrict__ vf,
      unsigned short* __restrict__ xbf,
      const float* __restrict__ bnmean, const float* __restrict__ bnscale,
      const float* __restrict__ bnb, const int* __restrict__ hi){
  int M=hi[10]; int total=M*FEAT;
  for(int i=blockIdx.x*blockDim.x+threadIdx.x; i<total; i+=gridDim.x*blockDim.x){
    int c=i&127;
    float v=fmaxf((buf[i]-bnmean[c])*bnscale[c]+bnb[c]+vf[i], 0.f);
    vf[i]=v;
    xbf[i]=f2bf(v);
  }
}

// ---------------- output head ----------------
__global__ __launch_bounds__(256) void k_head(const float* __restrict__ vf, const int* __restrict__ inv,
    const float* __restrict__ w1, const float* __restrict__ b1,
    const float* __restrict__ w2, const float* __restrict__ b2, float* __restrict__ out){
  __shared__ float w1s[FEAT*HIDN];
  __shared__ float w2s[HIDN*GD];
  __shared__ float hs[PPB*HIDN];
  int tid=threadIdx.x;
  for(int i=tid;i<FEAT*HIDN;i+=256) w1s[i]=w1[i];
  for(int i=tid;i<HIDN*GD;i+=256) w2s[i]=w2[i];
  __syncthreads();
  int p0=blockIdx.x*PPB;
  int hid=tid&63, pl=tid>>6;
  float bb=b1[hid];
  for(int pp=pl; pp<PPB; pp+=4){
    const float* pf=vf+(size_t)inv[p0+pp]*FEAT;
    float a=bb;
    #pragma unroll 4
    for(int c=0;c<FEAT;c++) a=fmaf(pf[c], w1s[c*HIDN+hid], a);
    hs[pp*HIDN+hid]=fmaxf(a,0.f);
  }
  __syncthreads();
  for(int i=tid;i<PPB*GD;i+=256){
    int pp=i/GD, o=i-pp*GD;
    const float* h=&hs[pp*HIDN];
    float a=b2[o];
    #pragma unroll
    for(int j=0;j<HIDN;j++) a=fmaf(h[j], w2s[j*GD+o], a);
    out[(size_t)(p0+pp)*GD+o]=a;
  }
}

extern "C" void kernel_launch(void* const* d_in, const int* in_sizes, int n_in,
                              void* d_out, int out_size, void* d_ws, size_t ws_size,
                              hipStream_t stream) {
  if(ws_size < WS_NEED) return;
  const float* gp  =(const float*)d_in[0];
  const float* psin=(const float*)d_in[1];
  const float* w_in=(const float*)d_in[2];
  const float* b_in=(const float*)d_in[3];
  const float* ln_g=(const float*)d_in[4];
  const float* ln_b=(const float*)d_in[5];
  const float* cw1 =(const float*)d_in[6];
  const float* bn1g=(const float*)d_in[7];
  const float* bn1b=(const float*)d_in[8];
  const float* cw2 =(const float*)d_in[9];
  const float* bn2g=(const float*)d_in[10];
  const float* bn2b=(const float*)d_in[11];
  const float* wh1 =(const float*)d_in[12];
  const float* bh1 =(const float*)d_in[13];
  const float* wh2 =(const float*)d_in[14];
  const float* bh2 =(const float*)d_in[15];
  float* out=(float*)d_out;

  char* ws=(char*)d_ws;
  int*    hi    =(int*)(ws+OFF_HDR);
  float*  hf    =(float*)(ws+OFF_HDR);
  double* bnsum =(double*)(ws+OFF_HDR+2048);
  double* bnsq  =(double*)(ws+OFF_HDR+3072);
  float*  bnmean=(float*)(ws+OFF_HDR+4096);
  float*  bnscal=(float*)(ws+OFF_HDR+4608);
  double* redp  =(double*)(ws+OFF_RED);
  int*    tkeys =(int*)(ws+OFF_TKEY);
  int*    tslot =(int*)(ws+OFF_TSLOT);
  int*    tidx  =(int*)(ws+OFF_TIDX);
  int*    inv   =(int*)(ws+OFF_INV);
  int*    voxh  =(int*)(ws+OFF_VOXH);
  int*    cnt   =(int*)(ws+OFF_CNT);
  int*    vc    =(int*)(ws+OFF_VC);
  int*    nbr   =(int*)(ws+OFF_NBR);
  unsigned short* wt =(unsigned short*)(ws+OFF_WT);
  unsigned short* xbf=(unsigned short*)(ws+OFF_XBF);
  float*  vf    =(float*)(ws+OFF_VF);
  float*  ybuf  =(float*)(ws+OFF_YB);

  hipMemsetAsync(tkeys,0xFF,(size_t)TSIZE*4,stream);
  hipMemsetAsync(vf,0,(size_t)N_PTSC*FEAT*4,stream);
  hipMemsetAsync(cnt,0,(size_t)N_PTSC*4,stream);

  k_red1<<<RED_BLOCKS,256,0,stream>>>(gp,psin,redp);
  k_red2<<<1,256,0,stream>>>(redp,hi,hf);
  k_vc<<<256,256,0,stream>>>(gp,psin,hf,hi,vc);
  k_grid<<<1,64,0,stream>>>(hi);
  k_hash<<<N_PTSC/256,256,0,stream>>>(vc,hi,tkeys,tidx);
  k_slot<<<TSIZE/256,256,0,stream>>>(tkeys,tslot,voxh,hi);
  k_wprep<<<(4*27*FEAT*FEAT)/256,256,0,stream>>>(cw1,cw2,wt);
  k_pool<<<N_PTSC/4,256,0,stream>>>(gp,w_in,b_in,ln_g,ln_b,tidx,tslot,inv,cnt,vf);
  k_div<<<2048,256,0,stream>>>(vf,xbf,cnt,hi);
  k_nbr<<<2048,256,0,stream>>>(voxh,tkeys,tslot,hi,nbr);

  for(int l=0;l<2;l++){
    k_conv<<<N_PTSC/128,256,0,stream>>>(xbf,ybuf,wt+((size_t)(l*2+0)*27)*FEAT*FEAT,nbr,hi);
    hipMemsetAsync(bnsum,0,2048,stream);
    k_bnstat<<<512,128,0,stream>>>(ybuf,hi,bnsum,bnsq);
    k_bnfinish<<<1,128,0,stream>>>(bnsum,bnsq,hi,bn1g+(size_t)l*FEAT,bnmean,bnscal);
    k_bnapply_relu<<<2048,256,0,stream>>>(ybuf,xbf,bnmean,bnscal,bn1b+(size_t)l*FEAT,hi);

    k_conv<<<N_PTSC/128,256,0,stream>>>(xbf,ybuf,wt+((size_t)(l*2+1)*27)*FEAT*FEAT,nbr,hi);
    hipMemsetAsync(bnsum,0,2048,stream);
    k_bnstat<<<512,128,0,stream>>>(ybuf,hi,bnsum,bnsq);
    k_bnfinish<<<1,128,0,stream>>>(bnsum,bnsq,hi,bn2g+(size_t)l*FEAT,bnmean,bnscal);
    k_bnapply_res<<<2048,256,0,stream>>>(ybuf,vf,xbf,bnmean,bnscal,bn2b+(size_t)l*FEAT,hi);
  }

  k_head<<<N_PTSC/PPB,256,0,stream>>>(vf,inv,wh1,bh1,wh2,bh2,out);
}

// Round 3
// 1538.655 us; speedup vs baseline: 34.1150x; 1.8391x over previous
//
#include <hip/hip_runtime.h>
#include <hip/hip_bf16.h>
#include <math.h>
#include <limits.h>

#define N_PTSC 131072
#define NSHIFT 17
#define GD 14
#define FEAT 128
#define HIDN 64
#define TBITS 19
#define TSIZE (1<<TBITS)
#define EMPTY_KEY (-1)
#define VOXEL 0.05f
#define EPSC 1e-5f
#define RED_BLOCKS 256
#define PPB 32
#define CONV_TV 256
#define NB_CONV (N_PTSC/CONV_TV)

typedef __attribute__((ext_vector_type(8))) short short8;
typedef __attribute__((ext_vector_type(4))) float f32x4;

// ---------------- workspace layout (bytes) ----------------
// header[0,8192): hi[0..5]=vc min/max, hi[6..8]=mx, hi[9]=m12, hi[10]=M
//                 hf[16..18]=pos mean; @4096 float bnsum[4][128]; @6144 float bnsq[4][128]
#define OFF_HDR   0
#define OFF_BNS   4096
#define OFF_BNQ   6144
#define OFF_RED   8192
#define OFF_TKEY  16384
#define OFF_TSLOT (OFF_TKEY + (size_t)TSIZE*4)
#define OFF_TIDX  (OFF_TSLOT + (size_t)TSIZE*4)
#define OFF_INV   (OFF_TIDX + (size_t)N_PTSC*4)
#define OFF_VOXH  (OFF_INV + (size_t)N_PTSC*4)
#define OFF_CNT   (OFF_VOXH + (size_t)N_PTSC*4)
#define OFF_VC    (OFF_CNT + (size_t)N_PTSC*4)
#define OFF_NBR   (OFF_VC + (size_t)N_PTSC*12)
#define OFF_WT    (OFF_NBR + (size_t)N_PTSC*27*4)
#define OFF_XBF   (OFF_WT + (size_t)4*27*FEAT*FEAT*2)
#define OFF_VF    (OFF_XBF + (size_t)N_PTSC*FEAT*2)
#define OFF_YB    (OFF_VF + (size_t)N_PTSC*FEAT*4)
#define WS_NEED   (OFF_YB + (size_t)N_PTSC*FEAT*4)

__device__ __forceinline__ float cleanf(float x){
  if(__builtin_isnan(x)) return 0.f;
  if(__builtin_isinf(x)) return x>0.f?1.f:-1.f;
  return x;
}
__device__ __forceinline__ float get_ps(const float* p){
  float v=p[0];
  return (__builtin_isfinite(v) && v!=0.f) ? v : 1.f;
}
__device__ __forceinline__ unsigned hashh(int h){
  return ((unsigned)h*2654435761u)>>(32-TBITS);
}
__device__ __forceinline__ unsigned short f2bf(float x){
  __hip_bfloat16 h=__float2bfloat16(x);
  return *reinterpret_cast<unsigned short*>(&h);
}

// ---------------- mean reduction ----------------
__global__ __launch_bounds__(256) void k_red1(const float* __restrict__ gp, const float* __restrict__ psin,
                                              double* __restrict__ redp){
  float ps=get_ps(psin);
  int tid=threadIdx.x;
  double s0=0,s1=0,s2=0;
  for(int i=blockIdx.x*256+tid; i<N_PTSC; i+=RED_BLOCKS*256){
    const float* g=gp+(size_t)i*GD;
    s0+=(double)(cleanf(g[0])/ps);
    s1+=(double)(cleanf(g[1])/ps);
    s2+=(double)(cleanf(g[2])/ps);
  }
  __shared__ double sm[3][256];
  sm[0][tid]=s0; sm[1][tid]=s1; sm[2][tid]=s2;
  __syncthreads();
  for(int s=128;s>0;s>>=1){
    if(tid<s){ sm[0][tid]+=sm[0][tid+s]; sm[1][tid]+=sm[1][tid+s]; sm[2][tid]+=sm[2][tid+s]; }
    __syncthreads();
  }
  if(tid==0){ redp[blockIdx.x*3+0]=sm[0][0]; redp[blockIdx.x*3+1]=sm[1][0]; redp[blockIdx.x*3+2]=sm[2][0]; }
}

__global__ __launch_bounds__(256) void k_red2(const double* __restrict__ redp, int* __restrict__ hi, float* __restrict__ hf){
  int tid=threadIdx.x;
  __shared__ double sm[3][256];
  sm[0][tid]=redp[tid*3+0]; sm[1][tid]=redp[tid*3+1]; sm[2][tid]=redp[tid*3+2];
  __syncthreads();
  for(int s=128;s>0;s>>=1){
    if(tid<s){ sm[0][tid]+=sm[0][tid+s]; sm[1][tid]+=sm[1][tid+s]; sm[2][tid]+=sm[2][tid+s]; }
    __syncthreads();
  }
  if(tid==0){
    hf[16]=(float)(sm[0][0]/(double)N_PTSC);
    hf[17]=(float)(sm[1][0]/(double)N_PTSC);
    hf[18]=(float)(sm[2][0]/(double)N_PTSC);
    hi[0]=INT_MAX; hi[1]=INT_MAX; hi[2]=INT_MAX;
    hi[3]=INT_MIN; hi[4]=INT_MIN; hi[5]=INT_MIN;
    hi[10]=0;
  }
}

// ---------------- voxel coords + extents ----------------
__global__ __launch_bounds__(256) void k_vc(const float* __restrict__ gp, const float* __restrict__ psin,
                                            const float* __restrict__ hf, int* __restrict__ hi, int* __restrict__ vc){
  float ps=get_ps(psin);
  float m0=hf[16], m1=hf[17], m2=hf[18];
  int mn0=INT_MAX,mn1=INT_MAX,mn2=INT_MAX,mx0=INT_MIN,mx1=INT_MIN,mx2=INT_MIN;
  for(int i=blockIdx.x*blockDim.x+threadIdx.x; i<N_PTSC; i+=gridDim.x*blockDim.x){
    const float* g=gp+(size_t)i*GD;
    int v0=(int)floorf((cleanf(g[0])/ps - m0)/VOXEL);
    int v1=(int)floorf((cleanf(g[1])/ps - m1)/VOXEL);
    int v2=(int)floorf((cleanf(g[2])/ps - m2)/VOXEL);
    vc[i]=v0; vc[N_PTSC+i]=v1; vc[2*N_PTSC+i]=v2;
    mn0=min(mn0,v0); mn1=min(mn1,v1); mn2=min(mn2,v2);
    mx0=max(mx0,v0); mx1=max(mx1,v1); mx2=max(mx2,v2);
  }
  __shared__ int sb[6][256];
  int tid=threadIdx.x;
  sb[0][tid]=mn0; sb[1][tid]=mn1; sb[2][tid]=mn2;
  sb[3][tid]=mx0; sb[4][tid]=mx1; sb[5][tid]=mx2;
  __syncthreads();
  for(int s=128;s>0;s>>=1){
    if(tid<s){
      #pragma unroll
      for(int d=0;d<3;d++){
        sb[d][tid]=min(sb[d][tid],sb[d][tid+s]);
        sb[3+d][tid]=max(sb[3+d][tid],sb[3+d][tid+s]);
      }
    }
    __syncthreads();
  }
  if(tid==0){
    atomicMin(&hi[0],sb[0][0]); atomicMin(&hi[1],sb[1][0]); atomicMin(&hi[2],sb[2][0]);
    atomicMax(&hi[3],sb[3][0]); atomicMax(&hi[4],sb[4][0]); atomicMax(&hi[5],sb[5][0]);
  }
}

__global__ void k_grid(int* hi){
  if(threadIdx.x==0&&blockIdx.x==0){
    int mx0=hi[3]-hi[0]+1, mx1=hi[4]-hi[1]+1, mx2=hi[5]-hi[2]+1;
    hi[6]=mx0; hi[7]=mx1; hi[8]=mx2; hi[9]=mx1*mx2;
  }
}

// ---------------- hash insert + slot assignment ----------------
__global__ __launch_bounds__(256) void k_hash(const int* __restrict__ vc, const int* __restrict__ hi,
                                              int* __restrict__ tkeys, int* __restrict__ tidx){
  int i=blockIdx.x*256+threadIdx.x;
  if(i>=N_PTSC) return;
  int mn0=hi[0],mn1=hi[1],mn2=hi[2],mx2=hi[8],m12=hi[9];
  int h=(vc[i]-mn0)*m12 + (vc[N_PTSC+i]-mn1)*mx2 + (vc[2*N_PTSC+i]-mn2);
  unsigned idx=hashh(h);
  while(true){
    int k=atomicCAS(&tkeys[idx],EMPTY_KEY,h);
    if(k==EMPTY_KEY||k==h) break;
    idx=(idx+1)&(TSIZE-1);
  }
  tidx[i]=(int)idx;
}

__global__ __launch_bounds__(256) void k_slot(const int* __restrict__ tkeys, int* __restrict__ tslot,
                                              int* __restrict__ voxh, int* __restrict__ hi){
  int t=blockIdx.x*256+threadIdx.x;
  if(t>=TSIZE) return;
  int k=tkeys[t];
  if(k!=EMPTY_KEY){
    int s=atomicAdd(&hi[10],1);
    tslot[t]=s;
    voxh[s]=k;
  }
}

// ---------------- weight prep: transpose + bf16; wt[lc][k][o][i] ----------------
__global__ __launch_bounds__(256) void k_wprep(const float* __restrict__ w1, const float* __restrict__ w2,
                                               unsigned short* __restrict__ wt){
  int t=blockIdx.x*256+threadIdx.x;
  int i=t&127, o=(t>>7)&127, r=t>>14;
  int k=r%27, lc=r/27;
  int l=lc>>1, c=lc&1;
  const float* src=(c==0)?w1:w2;
  wt[t]=f2bf(src[(((size_t)l*27+k)*128+i)*128+o]);
}

// ---------------- input encoder + LN + ReLU + mean-pool (wave per point) ----------------
__global__ __launch_bounds__(256) void k_pool(const float* __restrict__ gp,
    const float* __restrict__ w_in, const float* __restrict__ b_in,
    const float* __restrict__ ln_g, const float* __restrict__ ln_b,
    const int* __restrict__ tidx, const int* __restrict__ tslot,
    int* __restrict__ inv, int* __restrict__ cnt, float* __restrict__ vf){
  int p=blockIdx.x*4+(threadIdx.x>>6);
  int l=threadIdx.x&63;
  float x[GD];
  #pragma unroll
  for(int j=0;j<GD;j++) x[j]=cleanf(gp[(size_t)p*GD+j]);
  float a0=b_in[l], a1=b_in[l+64];
  #pragma unroll
  for(int j=0;j<GD;j++){
    a0=fmaf(x[j], w_in[j*FEAT+l], a0);
    a1=fmaf(x[j], w_in[j*FEAT+64+l], a1);
  }
  float s=a0+a1;
  #pragma unroll
  for(int off=32;off>0;off>>=1) s+=__shfl_xor(s,off);
  float mu=s*(1.f/FEAT);
  float d0=a0-mu, d1=a1-mu;
  float q=d0*d0+d1*d1;
  #pragma unroll
  for(int off=32;off>0;off>>=1) q+=__shfl_xor(q,off);
  float rs=rsqrtf(q*(1.f/FEAT)+EPSC);
  float y0=fmaxf(d0*rs*ln_g[l]+ln_b[l],0.f);
  float y1=fmaxf(d1*rs*ln_g[64+l]+ln_b[64+l],0.f);
  int slot=tslot[tidx[p]];
  if(l==0){ inv[p]=slot; atomicAdd(&cnt[slot],1); }
  atomicAdd(&vf[(size_t)slot*FEAT+l], y0);
  atomicAdd(&vf[(size_t)slot*FEAT+64+l], y1);
}

__global__ __launch_bounds__(256) void k_div(float* __restrict__ vf, unsigned short* __restrict__ xbf,
                                             const int* __restrict__ cnt, const int* __restrict__ hi){
  int M=hi[10];
  int total=M*FEAT;
  for(int i=blockIdx.x*blockDim.x+threadIdx.x; i<total; i+=gridDim.x*blockDim.x){
    int slot=i>>7;
    float v=vf[i]/(float)max(cnt[slot],1);
    vf[i]=v;
    xbf[i]=f2bf(v);
  }
}

// ---------------- neighbor table, tap-major: nbr[k<<17 | slot] ----------------
__global__ __launch_bounds__(256) void k_nbr(const int* __restrict__ voxh, const int* __restrict__ tkeys,
                                             const int* __restrict__ tslot, const int* __restrict__ hi,
                                             int* __restrict__ nbr){
  int M=hi[10];
  int mx0=hi[6],mx1=hi[7],mx2=hi[8],m12=hi[9];
  int total=27<<NSHIFT;
  for(int i=blockIdx.x*blockDim.x+threadIdx.x; i<total; i+=gridDim.x*blockDim.x){
    int s=i&(N_PTSC-1), k=i>>NSHIFT;
    if(s>=M) continue;
    int h=voxh[s];
    int c0=h/m12; int r=h-c0*m12; int c1=r/mx2; int c2=r-c1*mx2;
    int n0=c0+k/9-1, n1=c1+(k/3)%3-1, n2=c2+k%3-1;
    int res=-1;
    if(n0>=0&&n0<mx0&&n1>=0&&n1<mx1&&n2>=0&&n2<mx2){
      int nh=n0*m12+n1*mx2+n2;
      unsigned idx=hashh(nh);
      while(true){
        int kk=tkeys[idx];
        if(kk==nh){ res=tslot[idx]; break; }
        if(kk==EMPTY_KEY) break;
        idx=(idx+1)&(TSIZE-1);
      }
    }
    nbr[i]=res;
  }
}

// ---------------- submanifold conv: MFMA, LDS-staged double-buffered W ----------------
// 512 thr = 8 waves (4 row-groups x 2 col-groups); block = 256 voxels x 128 cols.
// Wave tile = 64 rows x 64 cols; acc[4][4] f32x4 = 64 VGPR.
// W[k] (32KB bf16) double-buffered in LDS, 16B-granule XOR swizzle (balanced b128 r/w).
// Per tap: barrier -> issue W[k+1] global->reg + nbr[k+1] -> compute from Ws[cur]
// -> ds_write W[k+1] -> flip. BN stats fused into epilogue.
__global__ __launch_bounds__(512,4) void k_conv(const unsigned short* __restrict__ X,
      float* __restrict__ Y, const unsigned short* __restrict__ Wt,
      const int* __restrict__ nbr, const int* __restrict__ hi,
      float* __restrict__ bnsum, float* __restrict__ bnsq){
  int M=hi[10];
  int v0=blockIdx.x*CONV_TV;
  if(v0>=M) return;
  __shared__ unsigned short Ws[2][FEAT*FEAT];  // 64KB
  __shared__ float bsum[FEAT], bsq[FEAT];
  int tid=threadIdx.x;
  int wid=tid>>6, l=tid&63;
  int wr=wid>>1, wc=wid&1;
  int g=l>>4, ln=l&15;
  int rbase=v0+wr*64;
  int cbase=wc*64;
  f32x4 acc[4][4];
  #pragma unroll
  for(int rt=0;rt<4;rt++)
    #pragma unroll
    for(int nt=0;nt<4;nt++)
      acc[rt][nt]=(f32x4){0.f,0.f,0.f,0.f};
  short8 zf={0,0,0,0,0,0,0,0};
  if(tid<FEAT){ bsum[tid]=0.f; bsq[tid]=0.f; }
  // prologue: stage W[0] -> Ws[0]; nbr for tap 0
  {
    uint4 wreg[4];
    #pragma unroll
    for(int j=0;j<4;j++) wreg[j]=*(const uint4*)(Wt+(size_t)(j*512+tid)*8);
    #pragma unroll
    for(int j=0;j<4;j++){
      int gi=j*512+tid; int col=gi>>4, sub=gi&15;
      *(uint4*)&Ws[0][(size_t)(col*16+(sub^(col&15)))*8]=wreg[j];
    }
  }
  int nbc[4];
  #pragma unroll
  for(int rt=0;rt<4;rt++){
    int r=rbase+rt*16+ln;
    nbc[rt]=(r<M)?nbr[r]:-1;
  }
  int cur=0;
  for(int k=0;k<27;k++){
    __syncthreads();   // Ws[cur] ready, Ws[cur^1] free
    uint4 wreg[4]; int nbn[4];
    if(k<26){
      const unsigned short* wk=Wt+(size_t)(k+1)*FEAT*FEAT;
      #pragma unroll
      for(int j=0;j<4;j++) wreg[j]=*(const uint4*)(wk+(size_t)(j*512+tid)*8);
      int kb=(k+1)<<NSHIFT;
      #pragma unroll
      for(int rt=0;rt<4;rt++){
        int r=rbase+rt*16+ln;
        nbn[rt]=(r<M)?nbr[kb+r]:-1;
      }
    }
    unsigned rtm=0;
    #pragma unroll
    for(int rt=0;rt<4;rt++) if(__ballot(nbc[rt]>=0)) rtm|=1u<<rt;
    if(rtm){
      #pragma unroll
      for(int ks=0;ks<4;ks++){
        short8 a[4];
        #pragma unroll
        for(int rt=0;rt<4;rt++){
          a[rt]=zf;
          if(nbc[rt]>=0) a[rt]=*(const short8*)(X+(size_t)nbc[rt]*FEAT+ks*32+g*8);
        }
        #pragma unroll
        for(int nt=0;nt<4;nt++){
          int col=cbase+nt*16+ln;
          short8 b=*(const short8*)&Ws[cur][(size_t)(col*16+((ks*4+g)^ln))*8];
          #pragma unroll
          for(int rt=0;rt<4;rt++)
            if((rtm>>rt)&1u)
              acc[rt][nt]=__builtin_amdgcn_mfma_f32_16x16x32_bf16(a[rt],b,acc[rt][nt],0,0,0);
        }
      }
    }
    if(k<26){
      #pragma unroll
      for(int j=0;j<4;j++){
        int gi=j*512+tid; int col=gi>>4, sub=gi&15;
        *(uint4*)&Ws[cur^1][(size_t)(col*16+(sub^(col&15)))*8]=wreg[j];
      }
      #pragma unroll
      for(int rt=0;rt<4;rt++) nbc[rt]=nbn[rt];
      cur^=1;
    }
  }
  // epilogue: Y writes + fused BN partial sums
  #pragma unroll
  for(int nt=0;nt<4;nt++){
    int col=cbase+nt*16+ln;
    float s=0.f,q=0.f;
    #pragma unroll
    for(int rt=0;rt<4;rt++){
      int vb=rbase+rt*16+g*4;
      #pragma unroll
      for(int r=0;r<4;r++){
        int v=vb+r;
        if(v<M){
          float val=acc[rt][nt][r];
          Y[(size_t)v*FEAT+col]=val;
          s+=val; q+=val*val;
        }
      }
    }
    s+=__shfl_xor(s,16); s+=__shfl_xor(s,32);
    q+=__shfl_xor(q,16); q+=__shfl_xor(q,32);
    if(g==0){ atomicAdd(&bsum[col],s); atomicAdd(&bsq[col],q); }
  }
  __syncthreads();
  if(tid<FEAT){
    atomicAdd(&bnsum[tid],bsum[tid]);
    atomicAdd(&bnsq[tid],bsq[tid]);
  }
}

// ---------------- BN finish + apply (+ReLU / +residual), bf16 re-encode ----------------
__global__ __launch_bounds__(256) void k_bnapply_relu(const float* __restrict__ buf, unsigned short* __restrict__ xbf,
      const float* __restrict__ bnsum, const float* __restrict__ bnsq,
      const float* __restrict__ bng, const float* __restrict__ bnb, const int* __restrict__ hi){
  __shared__ float smu[FEAT], ssc[FEAT];
  int M=hi[10];
  if(threadIdx.x<FEAT){
    double Md=(double)(M>0?M:1);
    double mu=(double)bnsum[threadIdx.x]/Md;
    double var=(double)bnsq[threadIdx.x]/Md-mu*mu;
    if(var<0.0) var=0.0;
    smu[threadIdx.x]=(float)mu;
    ssc[threadIdx.x]=(float)(1.0/sqrt(var+(double)EPSC))*bng[threadIdx.x];
  }
  __syncthreads();
  int total=M*FEAT;
  for(int i=blockIdx.x*blockDim.x+threadIdx.x; i<total; i+=gridDim.x*blockDim.x){
    int c=i&127;
    xbf[i]=f2bf(fmaxf((buf[i]-smu[c])*ssc[c]+bnb[c], 0.f));
  }
}

__global__ __launch_bounds__(256) void k_bnapply_res(const float* __restrict__ buf, float* __restrict__ vf,
      unsigned short* __restrict__ xbf,
      const float* __restrict__ bnsum, const float* __restrict__ bnsq,
      const float* __restrict__ bng, const float* __restrict__ bnb, const int* __restrict__ hi){
  __shared__ float smu[FEAT], ssc[FEAT];
  int M=hi[10];
  if(threadIdx.x<FEAT){
    double Md=(double)(M>0?M:1);
    double mu=(double)bnsum[threadIdx.x]/Md;
    double var=(double)bnsq[threadIdx.x]/Md-mu*mu;
    if(var<0.0) var=0.0;
    smu[threadIdx.x]=(float)mu;
    ssc[threadIdx.x]=(float)(1.0/sqrt(var+(double)EPSC))*bng[threadIdx.x];
  }
  __syncthreads();
  int total=M*FEAT;
  for(int i=blockIdx.x*blockDim.x+threadIdx.x; i<total; i+=gridDim.x*blockDim.x){
    int c=i&127;
    float v=fmaxf((buf[i]-smu[c])*ssc[c]+bnb[c]+vf[i], 0.f);
    vf[i]=v;
    xbf[i]=f2bf(v);
  }
}

// ---------------- output head ----------------
__global__ __launch_bounds__(256) void k_head(const float* __restrict__ vf, const int* __restrict__ inv,
    const float* __restrict__ w1, const float* __restrict__ b1,
    const float* __restrict__ w2, const float* __restrict__ b2, float* __restrict__ out){
  __shared__ float w1s[FEAT*HIDN];
  __shared__ float w2s[HIDN*GD];
  __shared__ float hs[PPB*HIDN];
  int tid=threadIdx.x;
  for(int i=tid;i<FEAT*HIDN;i+=256) w1s[i]=w1[i];
  for(int i=tid;i<HIDN*GD;i+=256) w2s[i]=w2[i];
  __syncthreads();
  int p0=blockIdx.x*PPB;
  int hid=tid&63, pl=tid>>6;
  float bb=b1[hid];
  for(int pp=pl; pp<PPB; pp+=4){
    const float* pf=vf+(size_t)inv[p0+pp]*FEAT;
    float a=bb;
    #pragma unroll 4
    for(int c=0;c<FEAT;c++) a=fmaf(pf[c], w1s[c*HIDN+hid], a);
    hs[pp*HIDN+hid]=fmaxf(a,0.f);
  }
  __syncthreads();
  for(int i=tid;i<PPB*GD;i+=256){
    int pp=i/GD, o=i-pp*GD;
    const float* h=&hs[pp*HIDN];
    float a=b2[o];
    #pragma unroll
    for(int j=0;j<HIDN;j++) a=fmaf(h[j], w2s[j*GD+o], a);
    out[(size_t)(p0+pp)*GD+o]=a;
  }
}

extern "C" void kernel_launch(void* const* d_in, const int* in_sizes, int n_in,
                              void* d_out, int out_size, void* d_ws, size_t ws_size,
                              hipStream_t stream) {
  if(ws_size < WS_NEED) return;
  const float* gp  =(const float*)d_in[0];
  const float* psin=(const float*)d_in[1];
  const float* w_in=(const float*)d_in[2];
  const float* b_in=(const float*)d_in[3];
  const float* ln_g=(const float*)d_in[4];
  const float* ln_b=(const float*)d_in[5];
  const float* cw1 =(const float*)d_in[6];
  const float* bn1g=(const float*)d_in[7];
  const float* bn1b=(const float*)d_in[8];
  const float* cw2 =(const float*)d_in[9];
  const float* bn2g=(const float*)d_in[10];
  const float* bn2b=(const float*)d_in[11];
  const float* wh1 =(const float*)d_in[12];
  const float* bh1 =(const float*)d_in[13];
  const float* wh2 =(const float*)d_in[14];
  const float* bh2 =(const float*)d_in[15];
  float* out=(float*)d_out;

  char* ws=(char*)d_ws;
  int*    hi    =(int*)(ws+OFF_HDR);
  float*  hf    =(float*)(ws+OFF_HDR);
  float*  bnsA  =(float*)(ws+OFF_BNS);   // [4][128]
  float*  bnqA  =(float*)(ws+OFF_BNQ);   // [4][128]
  double* redp  =(double*)(ws+OFF_RED);
  int*    tkeys =(int*)(ws+OFF_TKEY);
  int*    tslot =(int*)(ws+OFF_TSLOT);
  int*    tidx  =(int*)(ws+OFF_TIDX);
  int*    inv   =(int*)(ws+OFF_INV);
  int*    voxh  =(int*)(ws+OFF_VOXH);
  int*    cnt   =(int*)(ws+OFF_CNT);
  int*    vc    =(int*)(ws+OFF_VC);
  int*    nbr   =(int*)(ws+OFF_NBR);
  unsigned short* wt =(unsigned short*)(ws+OFF_WT);
  unsigned short* xbf=(unsigned short*)(ws+OFF_XBF);
  float*  vf    =(float*)(ws+OFF_VF);
  float*  ybuf  =(float*)(ws+OFF_YB);

  hipMemsetAsync(tkeys,0xFF,(size_t)TSIZE*4,stream);
  hipMemsetAsync(vf,0,(size_t)N_PTSC*FEAT*4,stream);
  hipMemsetAsync(cnt,0,(size_t)N_PTSC*4,stream);
  hipMemsetAsync(ws+OFF_BNS,0,4096,stream);

  k_red1<<<RED_BLOCKS,256,0,stream>>>(gp,psin,redp);
  k_red2<<<1,256,0,stream>>>(redp,hi,hf);
  k_vc<<<256,256,0,stream>>>(gp,psin,hf,hi,vc);
  k_grid<<<1,64,0,stream>>>(hi);
  k_hash<<<N_PTSC/256,256,0,stream>>>(vc,hi,tkeys,tidx);
  k_slot<<<TSIZE/256,256,0,stream>>>(tkeys,tslot,voxh,hi);
  k_wprep<<<(4*27*FEAT*FEAT)/256,256,0,stream>>>(cw1,cw2,wt);
  k_pool<<<N_PTSC/4,256,0,stream>>>(gp,w_in,b_in,ln_g,ln_b,tidx,tslot,inv,cnt,vf);
  k_div<<<2048,256,0,stream>>>(vf,xbf,cnt,hi);
  k_nbr<<<2048,256,0,stream>>>(voxh,tkeys,tslot,hi,nbr);

  for(int l=0;l<2;l++){
    int j0=l*2, j1=l*2+1;
    k_conv<<<NB_CONV,512,0,stream>>>(xbf,ybuf,wt+((size_t)j0*27)*FEAT*FEAT,nbr,hi,bnsA+j0*FEAT,bnqA+j0*FEAT);
    k_bnapply_relu<<<2048,256,0,stream>>>(ybuf,xbf,bnsA+j0*FEAT,bnqA+j0*FEAT,bn1g+(size_t)l*FEAT,bn1b+(size_t)l*FEAT,hi);

    k_conv<<<NB_CONV,512,0,stream>>>(xbf,ybuf,wt+((size_t)j1*27)*FEAT*FEAT,nbr,hi,bnsA+j1*FEAT,bnqA+j1*FEAT);
    k_bnapply_res<<<2048,256,0,stream>>>(ybuf,vf,xbf,bnsA+j1*FEAT,bnqA+j1*FEAT,bn2g+(size_t)l*FEAT,bn2b+(size_t)l*FEAT,hi);
  }

  k_head<<<N_PTSC/PPB,256,0,stream>>>(vf,inv,wh1,bh1,wh2,bh2,out);
}

// Round 4
// 1229.896 us; speedup vs baseline: 42.6794x; 1.2510x over previous
//
#include <hip/hip_runtime.h>
#include <hip/hip_bf16.h>
#include <math.h>
#include <limits.h>

#define N_PTSC 131072
#define NSHIFT 17
#define GD 14
#define FEAT 128
#define HIDN 64
#define TBITS 19
#define TSIZE (1<<TBITS)
#define EMPTY_KEY (-1)
#define VOXEL 0.05f
#define EPSC 1e-5f
#define RED_BLOCKS 256
#define NBUCK 16384
#define CONV_TV 256
#define NB_CONV (N_PTSC/CONV_TV)

typedef __attribute__((ext_vector_type(8))) short short8;
typedef __attribute__((ext_vector_type(4))) float f32x4;

// ---------------- workspace layout (bytes) ----------------
// header: hi[0..5]=vc min/max, hi[6..8]=mx, hi[9]=m12, hi[10]=M, hi[11]=bucket shift
//         hf[16..18]=pos mean; @4096 float bnsum[4][128]; @6144 float bnsq[4][128]
#define OFF_HDR   0
#define OFF_BNS   4096
#define OFF_BNQ   6144
#define OFF_RED   8192
#define OFF_HIST  16384
#define OFF_TKEY  (OFF_HIST + (size_t)NBUCK*4)
#define OFF_TSLOT (OFF_TKEY + (size_t)TSIZE*4)
#define OFF_TIDX  (OFF_TSLOT + (size_t)TSIZE*4)
#define OFF_INV   (OFF_TIDX + (size_t)N_PTSC*4)
#define OFF_VOXH  (OFF_INV + (size_t)N_PTSC*4)
#define OFF_CNT   (OFF_VOXH + (size_t)N_PTSC*4)
#define OFF_VC    (OFF_CNT + (size_t)N_PTSC*4)
#define OFF_NBR   (OFF_VC + (size_t)N_PTSC*12)
#define OFF_WT    (OFF_NBR + (size_t)N_PTSC*27*4)
#define OFF_XBF   (OFF_WT + (size_t)4*27*FEAT*FEAT*2)
#define OFF_VF    (OFF_XBF + (size_t)N_PTSC*FEAT*2)
#define OFF_YB    (OFF_VF + (size_t)N_PTSC*FEAT*4)
#define WS_NEED   (OFF_YB + (size_t)N_PTSC*FEAT*4)

__device__ __forceinline__ float cleanf(float x){
  if(__builtin_isnan(x)) return 0.f;
  if(__builtin_isinf(x)) return x>0.f?1.f:-1.f;
  return x;
}
__device__ __forceinline__ float get_ps(const float* p){
  float v=p[0];
  return (__builtin_isfinite(v) && v!=0.f) ? v : 1.f;
}
__device__ __forceinline__ unsigned hashh(int h){
  return ((unsigned)h*2654435761u)>>(32-TBITS);
}
__device__ __forceinline__ unsigned short f2bf(float x){
  __hip_bfloat16 h=__float2bfloat16(x);
  return *reinterpret_cast<unsigned short*>(&h);
}

// ---------------- mean reduction ----------------
__global__ __launch_bounds__(256) void k_red1(const float* __restrict__ gp, const float* __restrict__ psin,
                                              double* __restrict__ redp){
  float ps=get_ps(psin);
  int tid=threadIdx.x;
  double s0=0,s1=0,s2=0;
  for(int i=blockIdx.x*256+tid; i<N_PTSC; i+=RED_BLOCKS*256){
    const float* g=gp+(size_t)i*GD;
    s0+=(double)(cleanf(g[0])/ps);
    s1+=(double)(cleanf(g[1])/ps);
    s2+=(double)(cleanf(g[2])/ps);
  }
  __shared__ double sm[3][256];
  sm[0][tid]=s0; sm[1][tid]=s1; sm[2][tid]=s2;
  __syncthreads();
  for(int s=128;s>0;s>>=1){
    if(tid<s){ sm[0][tid]+=sm[0][tid+s]; sm[1][tid]+=sm[1][tid+s]; sm[2][tid]+=sm[2][tid+s]; }
    __syncthreads();
  }
  if(tid==0){ redp[blockIdx.x*3+0]=sm[0][0]; redp[blockIdx.x*3+1]=sm[1][0]; redp[blockIdx.x*3+2]=sm[2][0]; }
}

__global__ __launch_bounds__(256) void k_red2(const double* __restrict__ redp, int* __restrict__ hi, float* __restrict__ hf){
  int tid=threadIdx.x;
  __shared__ double sm[3][256];
  sm[0][tid]=redp[tid*3+0]; sm[1][tid]=redp[tid*3+1]; sm[2][tid]=redp[tid*3+2];
  __syncthreads();
  for(int s=128;s>0;s>>=1){
    if(tid<s){ sm[0][tid]+=sm[0][tid+s]; sm[1][tid]+=sm[1][tid+s]; sm[2][tid]+=sm[2][tid+s]; }
    __syncthreads();
  }
  if(tid==0){
    hf[16]=(float)(sm[0][0]/(double)N_PTSC);
    hf[17]=(float)(sm[1][0]/(double)N_PTSC);
    hf[18]=(float)(sm[2][0]/(double)N_PTSC);
    hi[0]=INT_MAX; hi[1]=INT_MAX; hi[2]=INT_MAX;
    hi[3]=INT_MIN; hi[4]=INT_MIN; hi[5]=INT_MIN;
    hi[10]=0;
  }
}

// ---------------- voxel coords + extents ----------------
__global__ __launch_bounds__(256) void k_vc(const float* __restrict__ gp, const float* __restrict__ psin,
                                            const float* __restrict__ hf, int* __restrict__ hi, int* __restrict__ vc){
  float ps=get_ps(psin);
  float m0=hf[16], m1=hf[17], m2=hf[18];
  int mn0=INT_MAX,mn1=INT_MAX,mn2=INT_MAX,mx0=INT_MIN,mx1=INT_MIN,mx2=INT_MIN;
  for(int i=blockIdx.x*blockDim.x+threadIdx.x; i<N_PTSC; i+=gridDim.x*blockDim.x){
    const float* g=gp+(size_t)i*GD;
    int v0=(int)floorf((cleanf(g[0])/ps - m0)/VOXEL);
    int v1=(int)floorf((cleanf(g[1])/ps - m1)/VOXEL);
    int v2=(int)floorf((cleanf(g[2])/ps - m2)/VOXEL);
    vc[i]=v0; vc[N_PTSC+i]=v1; vc[2*N_PTSC+i]=v2;
    mn0=min(mn0,v0); mn1=min(mn1,v1); mn2=min(mn2,v2);
    mx0=max(mx0,v0); mx1=max(mx1,v1); mx2=max(mx2,v2);
  }
  __shared__ int sb[6][256];
  int tid=threadIdx.x;
  sb[0][tid]=mn0; sb[1][tid]=mn1; sb[2][tid]=mn2;
  sb[3][tid]=mx0; sb[4][tid]=mx1; sb[5][tid]=mx2;
  __syncthreads();
  for(int s=128;s>0;s>>=1){
    if(tid<s){
      #pragma unroll
      for(int d=0;d<3;d++){
        sb[d][tid]=min(sb[d][tid],sb[d][tid+s]);
        sb[3+d][tid]=max(sb[3+d][tid],sb[3+d][tid+s]);
      }
    }
    __syncthreads();
  }
  if(tid==0){
    atomicMin(&hi[0],sb[0][0]); atomicMin(&hi[1],sb[1][0]); atomicMin(&hi[2],sb[2][0]);
    atomicMax(&hi[3],sb[3][0]); atomicMax(&hi[4],sb[4][0]); atomicMax(&hi[5],sb[5][0]);
  }
}

__global__ void k_grid(int* hi){
  if(threadIdx.x==0&&blockIdx.x==0){
    int mx0=hi[3]-hi[0]+1, mx1=hi[4]-hi[1]+1, mx2=hi[5]-hi[2]+1;
    hi[6]=mx0; hi[7]=mx1; hi[8]=mx2; hi[9]=mx1*mx2;
    int hmax=mx0*mx1*mx2;
    int sh=0;
    while((hmax>>sh)>=NBUCK) sh++;
    hi[11]=sh;
  }
}

// ---------------- hash insert ----------------
__global__ __launch_bounds__(256) void k_hash(const int* __restrict__ vc, const int* __restrict__ hi,
                                              int* __restrict__ tkeys, int* __restrict__ tidx){
  int i=blockIdx.x*256+threadIdx.x;
  if(i>=N_PTSC) return;
  int mn0=hi[0],mn1=hi[1],mn2=hi[2],mx2=hi[8],m12=hi[9];
  int h=(vc[i]-mn0)*m12 + (vc[N_PTSC+i]-mn1)*mx2 + (vc[2*N_PTSC+i]-mn2);
  unsigned idx=hashh(h);
  while(true){
    int k=atomicCAS(&tkeys[idx],EMPTY_KEY,h);
    if(k==EMPTY_KEY||k==h) break;
    idx=(idx+1)&(TSIZE-1);
  }
  tidx[i]=(int)idx;
}

// ---------------- spatial slot assignment: bucketed counting sort on h ----------------
__global__ __launch_bounds__(256) void k_hist(const int* __restrict__ tkeys, const int* __restrict__ hi,
                                              int* __restrict__ hist){
  int t=blockIdx.x*256+threadIdx.x;
  if(t>=TSIZE) return;
  int k=tkeys[t];
  if(k!=EMPTY_KEY) atomicAdd(&hist[k>>hi[11]],1);
}

__global__ __launch_bounds__(256) void k_scan(int* __restrict__ hist, int* __restrict__ hi){
  __shared__ int psum[256];
  int tid=threadIdx.x;
  int base=tid*(NBUCK/256);
  int s=0;
  for(int i=0;i<NBUCK/256;i++) s+=hist[base+i];
  psum[tid]=s;
  __syncthreads();
  for(int off=1;off<256;off<<=1){
    int v=(tid>=off)?psum[tid-off]:0;
    __syncthreads();
    psum[tid]+=v;
    __syncthreads();
  }
  int run=psum[tid]-s;   // exclusive prefix of this chunk
  for(int i=0;i<NBUCK/256;i++){
    int v=hist[base+i];
    hist[base+i]=run;
    run+=v;
  }
  if(tid==255) hi[10]=run;   // total active voxels M
}

__global__ __launch_bounds__(256) void k_slot2(const int* __restrict__ tkeys, const int* __restrict__ hi,
                                               int* __restrict__ hist, int* __restrict__ tslot,
                                               int* __restrict__ voxh){
  int t=blockIdx.x*256+threadIdx.x;
  if(t>=TSIZE) return;
  int k=tkeys[t];
  if(k==EMPTY_KEY) return;
  int s=atomicAdd(&hist[k>>hi[11]],1);
  tslot[t]=s;
  voxh[s]=k;
}

// ---------------- weight prep: transpose + bf16; wt[lc][k][o][i] ----------------
__global__ __launch_bounds__(256) void k_wprep(const float* __restrict__ w1, const float* __restrict__ w2,
                                               unsigned short* __restrict__ wt){
  int t=blockIdx.x*256+threadIdx.x;
  int i=t&127, o=(t>>7)&127, r=t>>14;
  int k=r%27, lc=r/27;
  int l=lc>>1, c=lc&1;
  const float* src=(c==0)?w1:w2;
  wt[t]=f2bf(src[(((size_t)l*27+k)*128+i)*128+o]);
}

// ---------------- input encoder + LN + ReLU + mean-pool (wave per point) ----------------
__global__ __launch_bounds__(256) void k_pool(const float* __restrict__ gp,
    const float* __restrict__ w_in, const float* __restrict__ b_in,
    const float* __restrict__ ln_g, const float* __restrict__ ln_b,
    const int* __restrict__ tidx, const int* __restrict__ tslot,
    int* __restrict__ inv, int* __restrict__ cnt, float* __restrict__ vf){
  int p=blockIdx.x*4+(threadIdx.x>>6);
  int l=threadIdx.x&63;
  float x[GD];
  #pragma unroll
  for(int j=0;j<GD;j++) x[j]=cleanf(gp[(size_t)p*GD+j]);
  float a0=b_in[l], a1=b_in[l+64];
  #pragma unroll
  for(int j=0;j<GD;j++){
    a0=fmaf(x[j], w_in[j*FEAT+l], a0);
    a1=fmaf(x[j], w_in[j*FEAT+64+l], a1);
  }
  float s=a0+a1;
  #pragma unroll
  for(int off=32;off>0;off>>=1) s+=__shfl_xor(s,off);
  float mu=s*(1.f/FEAT);
  float d0=a0-mu, d1=a1-mu;
  float q=d0*d0+d1*d1;
  #pragma unroll
  for(int off=32;off>0;off>>=1) q+=__shfl_xor(q,off);
  float rs=rsqrtf(q*(1.f/FEAT)+EPSC);
  float y0=fmaxf(d0*rs*ln_g[l]+ln_b[l],0.f);
  float y1=fmaxf(d1*rs*ln_g[64+l]+ln_b[64+l],0.f);
  int slot=tslot[tidx[p]];
  if(l==0){ inv[p]=slot; atomicAdd(&cnt[slot],1); }
  atomicAdd(&vf[(size_t)slot*FEAT+l], y0);
  atomicAdd(&vf[(size_t)slot*FEAT+64+l], y1);
}

__global__ __launch_bounds__(256) void k_div(float* __restrict__ vf, unsigned short* __restrict__ xbf,
                                             const int* __restrict__ cnt, const int* __restrict__ hi){
  int M=hi[10];
  int total=M*FEAT;
  for(int i=blockIdx.x*blockDim.x+threadIdx.x; i<total; i+=gridDim.x*blockDim.x){
    int slot=i>>7;
    float v=vf[i]/(float)max(cnt[slot],1);
    vf[i]=v;
    xbf[i]=f2bf(v);
  }
}

// ---------------- neighbor table, tap-major: nbr[k<<17 | slot] ----------------
__global__ __launch_bounds__(256) void k_nbr(const int* __restrict__ voxh, const int* __restrict__ tkeys,
                                             const int* __restrict__ tslot, const int* __restrict__ hi,
                                             int* __restrict__ nbr){
  int M=hi[10];
  int mx0=hi[6],mx1=hi[7],mx2=hi[8],m12=hi[9];
  int total=27<<NSHIFT;
  for(int i=blockIdx.x*blockDim.x+threadIdx.x; i<total; i+=gridDim.x*blockDim.x){
    int s=i&(N_PTSC-1), k=i>>NSHIFT;
    if(s>=M) continue;
    int h=voxh[s];
    int c0=h/m12; int r=h-c0*m12; int c1=r/mx2; int c2=r-c1*mx2;
    int n0=c0+k/9-1, n1=c1+(k/3)%3-1, n2=c2+k%3-1;
    int res=-1;
    if(n0>=0&&n0<mx0&&n1>=0&&n1<mx1&&n2>=0&&n2<mx2){
      int nh=n0*m12+n1*mx2+n2;
      unsigned idx=hashh(nh);
      while(true){
        int kk=tkeys[idx];
        if(kk==nh){ res=tslot[idx]; break; }
        if(kk==EMPTY_KEY) break;
        idx=(idx+1)&(TSIZE-1);
      }
    }
    nbr[i]=res;
  }
}

// ---------------- submanifold conv: MFMA, LDS-staged double-buffered W ----------------
__global__ __launch_bounds__(512,4) void k_conv(const unsigned short* __restrict__ X,
      float* __restrict__ Y, const unsigned short* __restrict__ Wt,
      const int* __restrict__ nbr, const int* __restrict__ hi,
      float* __restrict__ bnsum, float* __restrict__ bnsq){
  int M=hi[10];
  int v0=blockIdx.x*CONV_TV;
  if(v0>=M) return;
  __shared__ unsigned short Ws[2][FEAT*FEAT];  // 64KB
  __shared__ float bsum[FEAT], bsq[FEAT];
  int tid=threadIdx.x;
  int wid=tid>>6, l=tid&63;
  int wr=wid>>1, wc=wid&1;
  int g=l>>4, ln=l&15;
  int rbase=v0+wr*64;
  int cbase=wc*64;
  f32x4 acc[4][4];
  #pragma unroll
  for(int rt=0;rt<4;rt++)
    #pragma unroll
    for(int nt=0;nt<4;nt++)
      acc[rt][nt]=(f32x4){0.f,0.f,0.f,0.f};
  short8 zf={0,0,0,0,0,0,0,0};
  if(tid<FEAT){ bsum[tid]=0.f; bsq[tid]=0.f; }
  {
    uint4 wreg[4];
    #pragma unroll
    for(int j=0;j<4;j++) wreg[j]=*(const uint4*)(Wt+(size_t)(j*512+tid)*8);
    #pragma unroll
    for(int j=0;j<4;j++){
      int gi=j*512+tid; int col=gi>>4, sub=gi&15;
      *(uint4*)&Ws[0][(size_t)(col*16+(sub^(col&15)))*8]=wreg[j];
    }
  }
  int nbc[4];
  #pragma unroll
  for(int rt=0;rt<4;rt++){
    int r=rbase+rt*16+ln;
    nbc[rt]=(r<M)?nbr[r]:-1;
  }
  int cur=0;
  for(int k=0;k<27;k++){
    __syncthreads();
    uint4 wreg[4]; int nbn[4];
    if(k<26){
      const unsigned short* wk=Wt+(size_t)(k+1)*FEAT*FEAT;
      #pragma unroll
      for(int j=0;j<4;j++) wreg[j]=*(const uint4*)(wk+(size_t)(j*512+tid)*8);
      int kb=(k+1)<<NSHIFT;
      #pragma unroll
      for(int rt=0;rt<4;rt++){
        int r=rbase+rt*16+ln;
        nbn[rt]=(r<M)?nbr[kb+r]:-1;
      }
    }
    unsigned rtm=0;
    #pragma unroll
    for(int rt=0;rt<4;rt++) if(__ballot(nbc[rt]>=0)) rtm|=1u<<rt;
    if(rtm){
      #pragma unroll
      for(int ks=0;ks<4;ks++){
        short8 a[4];
        #pragma unroll
        for(int rt=0;rt<4;rt++){
          a[rt]=zf;
          if(nbc[rt]>=0) a[rt]=*(const short8*)(X+(size_t)nbc[rt]*FEAT+ks*32+g*8);
        }
        #pragma unroll
        for(int nt=0;nt<4;nt++){
          int col=cbase+nt*16+ln;
          short8 b=*(const short8*)&Ws[cur][(size_t)(col*16+((ks*4+g)^ln))*8];
          #pragma unroll
          for(int rt=0;rt<4;rt++)
            if((rtm>>rt)&1u)
              acc[rt][nt]=__builtin_amdgcn_mfma_f32_16x16x32_bf16(a[rt],b,acc[rt][nt],0,0,0);
        }
      }
    }
    if(k<26){
      #pragma unroll
      for(int j=0;j<4;j++){
        int gi=j*512+tid; int col=gi>>4, sub=gi&15;
        *(uint4*)&Ws[cur^1][(size_t)(col*16+(sub^(col&15)))*8]=wreg[j];
      }
      #pragma unroll
      for(int rt=0;rt<4;rt++) nbc[rt]=nbn[rt];
      cur^=1;
    }
  }
  #pragma unroll
  for(int nt=0;nt<4;nt++){
    int col=cbase+nt*16+ln;
    float s=0.f,q=0.f;
    #pragma unroll
    for(int rt=0;rt<4;rt++){
      int vb=rbase+rt*16+g*4;
      #pragma unroll
      for(int r=0;r<4;r++){
        int v=vb+r;
        if(v<M){
          float val=acc[rt][nt][r];
          Y[(size_t)v*FEAT+col]=val;
          s+=val; q+=val*val;
        }
      }
    }
    s+=__shfl_xor(s,16); s+=__shfl_xor(s,32);
    q+=__shfl_xor(q,16); q+=__shfl_xor(q,32);
    if(g==0){ atomicAdd(&bsum[col],s); atomicAdd(&bsq[col],q); }
  }
  __syncthreads();
  if(tid<FEAT){
    atomicAdd(&bnsum[tid],bsum[tid]);
    atomicAdd(&bnsq[tid],bsq[tid]);
  }
}

// ---------------- BN finish + apply ----------------
__global__ __launch_bounds__(256) void k_bnapply_relu(const float* __restrict__ buf, unsigned short* __restrict__ xbf,
      const float* __restrict__ bnsum, const float* __restrict__ bnsq,
      const float* __restrict__ bng, const float* __restrict__ bnb, const int* __restrict__ hi){
  __shared__ float smu[FEAT], ssc[FEAT];
  int M=hi[10];
  if(threadIdx.x<FEAT){
    double Md=(double)(M>0?M:1);
    double mu=(double)bnsum[threadIdx.x]/Md;
    double var=(double)bnsq[threadIdx.x]/Md-mu*mu;
    if(var<0.0) var=0.0;
    smu[threadIdx.x]=(float)mu;
    ssc[threadIdx.x]=(float)(1.0/sqrt(var+(double)EPSC))*bng[threadIdx.x];
  }
  __syncthreads();
  int total=M*FEAT;
  for(int i=blockIdx.x*blockDim.x+threadIdx.x; i<total; i+=gridDim.x*blockDim.x){
    int c=i&127;
    xbf[i]=f2bf(fmaxf((buf[i]-smu[c])*ssc[c]+bnb[c], 0.f));
  }
}

__global__ __launch_bounds__(256) void k_bnapply_res(const float* __restrict__ buf, float* __restrict__ vf,
      unsigned short* __restrict__ xbf,
      const float* __restrict__ bnsum, const float* __restrict__ bnsq,
      const float* __restrict__ bng, const float* __restrict__ bnb, const int* __restrict__ hi){
  __shared__ float smu[FEAT], ssc[FEAT];
  int M=hi[10];
  if(threadIdx.x<FEAT){
    double Md=(double)(M>0?M:1);
    double mu=(double)bnsum[threadIdx.x]/Md;
    double var=(double)bnsq[threadIdx.x]/Md-mu*mu;
    if(var<0.0) var=0.0;
    smu[threadIdx.x]=(float)mu;
    ssc[threadIdx.x]=(float)(1.0/sqrt(var+(double)EPSC))*bng[threadIdx.x];
  }
  __syncthreads();
  int total=M*FEAT;
  for(int i=blockIdx.x*blockDim.x+threadIdx.x; i<total; i+=gridDim.x*blockDim.x){
    int c=i&127;
    float v=fmaxf((buf[i]-smu[c])*ssc[c]+bnb[c]+vf[i], 0.f);
    vf[i]=v;
    xbf[i]=f2bf(v);
  }
}

// ---------------- output head: MFMA GEMM1 (128->64) + scalar GEMM2 (64->14) ----------------
// 256 thr = 4 waves; 128 points/block. Wave w: rows [w*32, w*32+32) (2 rt-tiles), all 64 cols.
// W1^T bf16 in LDS (granule-XOR swizzle, conflict-free b128); h f32 [128][65] in LDS.
__global__ __launch_bounds__(256) void k_headm(const unsigned short* __restrict__ X, const int* __restrict__ inv,
    const float* __restrict__ w1, const float* __restrict__ b1,
    const float* __restrict__ w2, const float* __restrict__ b2, float* __restrict__ out){
  __shared__ unsigned short w1t[HIDN*FEAT];   // 16KB, swizzled [out][in]
  __shared__ float hbuf[FEAT*65];             // 33.25KB
  __shared__ float w2s[HIDN*GD];
  __shared__ float b1s[HIDN];
  int tid=threadIdx.x;
  // stage W1^T (swizzled granules of 8 elems), w2, b1
  for(int e=tid;e<HIDN*FEAT;e+=256){
    int o=e>>7, in=e&127;
    int sub=in>>3, j=in&7;
    w1t[(o*16+(sub^(o&15)))*8+j]=f2bf(w1[in*HIDN+o]);
  }
  for(int i=tid;i<HIDN*GD;i+=256) w2s[i]=w2[i];
  if(tid<HIDN) b1s[tid]=b1[tid];
  __syncthreads();
  int p0=blockIdx.x*128;
  int w=tid>>6, l=tid&63;
  int g=l>>4, ln=l&15;
  int rbase=w*32;
  int gr[2];
  #pragma unroll
  for(int rt=0;rt<2;rt++) gr[rt]=inv[p0+rbase+rt*16+ln];
  f32x4 acc[2][4];
  #pragma unroll
  for(int rt=0;rt<2;rt++)
    #pragma unroll
    for(int nt=0;nt<4;nt++)
      acc[rt][nt]=(f32x4){0.f,0.f,0.f,0.f};
  #pragma unroll
  for(int ks=0;ks<4;ks++){
    short8 a[2];
    #pragma unroll
    for(int rt=0;rt<2;rt++)
      a[rt]=*(const short8*)(X+(size_t)gr[rt]*FEAT+ks*32+g*8);
    #pragma unroll
    for(int nt=0;nt<4;nt++){
      int col=nt*16+ln;
      short8 b=*(const short8*)&w1t[(size_t)(col*16+((ks*4+g)^(col&15)))*8];
      #pragma unroll
      for(int rt=0;rt<2;rt++)
        acc[rt][nt]=__builtin_amdgcn_mfma_f32_16x16x32_bf16(a[rt],b,acc[rt][nt],0,0,0);
    }
  }
  // bias + relu -> h LDS
  #pragma unroll
  for(int rt=0;rt<2;rt++){
    #pragma unroll
    for(int nt=0;nt<4;nt++){
      int col=nt*16+ln;
      float bb=b1s[col];
      #pragma unroll
      for(int r=0;r<4;r++){
        int row=rbase+rt*16+g*4+r;
        hbuf[row*65+col]=fmaxf(acc[rt][nt][r]+bb,0.f);
      }
    }
  }
  __syncthreads();
  // GEMM2: 2 threads per row, 7 outputs each
  int row=tid>>1, o0=(tid&1)*7;
  float a2[7];
  #pragma unroll
  for(int oi=0;oi<7;oi++) a2[oi]=b2[o0+oi];
  const float* hr=&hbuf[row*65];
  for(int j=0;j<HIDN;j++){
    float hv=hr[j];
    const float* wr=&w2s[j*GD+o0];
    #pragma unroll
    for(int oi=0;oi<7;oi++) a2[oi]=fmaf(hv,wr[oi],a2[oi]);
  }
  float* op=out+(size_t)(p0+row)*GD+o0;
  #pragma unroll
  for(int oi=0;oi<7;oi++) op[oi]=a2[oi];
}

extern "C" void kernel_launch(void* const* d_in, const int* in_sizes, int n_in,
                              void* d_out, int out_size, void* d_ws, size_t ws_size,
                              hipStream_t stream) {
  if(ws_size < WS_NEED) return;
  const float* gp  =(const float*)d_in[0];
  const float* psin=(const float*)d_in[1];
  const float* w_in=(const float*)d_in[2];
  const float* b_in=(const float*)d_in[3];
  const float* ln_g=(const float*)d_in[4];
  const float* ln_b=(const float*)d_in[5];
  const float* cw1 =(const float*)d_in[6];
  const float* bn1g=(const float*)d_in[7];
  const float* bn1b=(const float*)d_in[8];
  const float* cw2 =(const float*)d_in[9];
  const float* bn2g=(const float*)d_in[10];
  const float* bn2b=(const float*)d_in[11];
  const float* wh1 =(const float*)d_in[12];
  const float* bh1 =(const float*)d_in[13];
  const float* wh2 =(const float*)d_in[14];
  const float* bh2 =(const float*)d_in[15];
  float* out=(float*)d_out;

  char* ws=(char*)d_ws;
  int*    hi    =(int*)(ws+OFF_HDR);
  float*  hf    =(float*)(ws+OFF_HDR);
  float*  bnsA  =(float*)(ws+OFF_BNS);
  float*  bnqA  =(float*)(ws+OFF_BNQ);
  double* redp  =(double*)(ws+OFF_RED);
  int*    hist  =(int*)(ws+OFF_HIST);
  int*    tkeys =(int*)(ws+OFF_TKEY);
  int*    tslot =(int*)(ws+OFF_TSLOT);
  int*    tidx  =(int*)(ws+OFF_TIDX);
  int*    inv   =(int*)(ws+OFF_INV);
  int*    voxh  =(int*)(ws+OFF_VOXH);
  int*    cnt   =(int*)(ws+OFF_CNT);
  int*    vc    =(int*)(ws+OFF_VC);
  int*    nbr   =(int*)(ws+OFF_NBR);
  unsigned short* wt =(unsigned short*)(ws+OFF_WT);
  unsigned short* xbf=(unsigned short*)(ws+OFF_XBF);
  float*  vf    =(float*)(ws+OFF_VF);
  float*  ybuf  =(float*)(ws+OFF_YB);

  hipMemsetAsync(tkeys,0xFF,(size_t)TSIZE*4,stream);
  hipMemsetAsync(vf,0,(size_t)N_PTSC*FEAT*4,stream);
  hipMemsetAsync(cnt,0,(size_t)N_PTSC*4,stream);
  hipMemsetAsync(hist,0,(size_t)NBUCK*4,stream);
  hipMemsetAsync(ws+OFF_BNS,0,4096,stream);

  k_red1<<<RED_BLOCKS,256,0,stream>>>(gp,psin,redp);
  k_red2<<<1,256,0,stream>>>(redp,hi,hf);
  k_vc<<<256,256,0,stream>>>(gp,psin,hf,hi,vc);
  k_grid<<<1,64,0,stream>>>(hi);
  k_hash<<<N_PTSC/256,256,0,stream>>>(vc,hi,tkeys,tidx);
  k_hist<<<TSIZE/256,256,0,stream>>>(tkeys,hi,hist);
  k_scan<<<1,256,0,stream>>>(hist,hi);
  k_slot2<<<TSIZE/256,256,0,stream>>>(tkeys,hi,hist,tslot,voxh);
  k_wprep<<<(4*27*FEAT*FEAT)/256,256,0,stream>>>(cw1,cw2,wt);
  k_pool<<<N_PTSC/4,256,0,stream>>>(gp,w_in,b_in,ln_g,ln_b,tidx,tslot,inv,cnt,vf);
  k_div<<<2048,256,0,stream>>>(vf,xbf,cnt,hi);
  k_nbr<<<2048,256,0,stream>>>(voxh,tkeys,tslot,hi,nbr);

  for(int l=0;l<2;l++){
    int j0=l*2, j1=l*2+1;
    k_conv<<<NB_CONV,512,0,stream>>>(xbf,ybuf,wt+((size_t)j0*27)*FEAT*FEAT,nbr,hi,bnsA+j0*FEAT,bnqA+j0*FEAT);
    k_bnapply_relu<<<2048,256,0,stream>>>(ybuf,xbf,bnsA+j0*FEAT,bnqA+j0*FEAT,bn1g+(size_t)l*FEAT,bn1b+(size_t)l*FEAT,hi);

    k_conv<<<NB_CONV,512,0,stream>>>(xbf,ybuf,wt+((size_t)j1*27)*FEAT*FEAT,nbr,hi,bnsA+j1*FEAT,bnqA+j1*FEAT);
    k_bnapply_res<<<2048,256,0,stream>>>(ybuf,vf,xbf,bnsA+j1*FEAT,bnqA+j1*FEAT,bn2g+(size_t)l*FEAT,bn2b+(size_t)l*FEAT,hi);
  }

  k_headm<<<N_PTSC/128,256,0,stream>>>(xbf,inv,wh1,bh1,wh2,bh2,out);
}